// Round 1
// baseline (3881.281 us; speedup 1.0000x reference)
//
#include <hip/hip_runtime.h>
#include <hip/hip_bf16.h>
#include <math.h>

// GeneralGNN fp32 baseline.
// Stage plan:
//  kT    : transpose all 12 weight matrices into ws (k-major for GEMM staging)
//  memset: zero m/s/agg/colstats
//  kA    : Bias MLP (384->128->128->4) per edge -> w_buf, atomicMax m[src,h]
//  kB    : w_buf = exp(w-m[src]); atomicAdd s[src,h]
//  kC    : V MLP (256->128->128->128) per edge; attend=wbuf/s; atomicAdd agg[src,:]
//  kD    : dh = agg@Wo^T; x = h_V+dh -> xbuf; colstats0
//  kFin  : finalize bnorm0 -> a0,c0 (y = x*a+c)
//  kF1   : hidden = gelu(norm0(xbuf)@Wd1^T+bd1)  (N,512)
//  kF2   : y = norm0(xbuf) + hidden@Wd2^T+bd2 -> d_out[hV]; colstats1
//  kFin  : finalize bnorm1
//  kNorm : d_out[hV] normalized in place  (this is final h_V)
//  kI    : EdgeMLP (384->128->128->128) on [hV[src],hE,hV[dst]]; pre=hE+msg -> d_out[hE]; colstatsE
//  kFin  : finalize edge bnorm
//  kNorm : d_out[hE] normalized in place

#define NN 15000
#define EE 300000

// ---------- workspace layout (float offsets) ----------
#define O_Wv1t 0
#define O_Wv2t (O_Wv1t + 256*128)
#define O_Wv3t (O_Wv2t + 128*128)
#define O_Wb1t (O_Wv3t + 128*128)
#define O_Wb2t (O_Wb1t + 384*128)
#define O_Wb3t (O_Wb2t + 128*128)
#define O_Wot  (O_Wb3t + 128*4)
#define O_Wd1t (O_Wot  + 128*128)
#define O_Wd2t (O_Wd1t + 128*512)
#define O_We1t (O_Wd2t + 512*128)
#define O_We2t (O_We1t + 384*128)
#define O_We3t (O_We2t + 128*128)
#define O_WB   (O_We3t + 128*128)      // w_buf [E][4]
#define O_M    (O_WB + EE*4)           // m (encoded uint) [N][4]
#define O_S    (O_M + NN*4)            // s [N][4]
#define O_AGG  (O_S + NN*4)            // agg [N][128]
#define O_STAT (O_AGG + NN*128)        // 3 x (sum[128], sumsq[128])
#define O_AB   (O_STAT + 768)          // 3 x (a[128], c[128])
#define O_XB   (O_AB + 768)            // xbuf [N][128] (pre-norm0)
#define O_HID  (O_XB + NN*128)         // hidden [N][512]

struct SMem {
  float act[128][132];   // k-major activations [k][row], pad->bank spread
  float ws[16][128];     // weight k-slice
  int   idx[256];        // src[128], dst[128]
  float cp[256];         // column partial sums for stats
};

__device__ inline float gelu_f(float x){
  return 0.5f*x*(1.0f + erff(x*0.70710678118654752f));
}
__device__ inline unsigned fenc(float f){
  unsigned u = __float_as_uint(f);
  return (u & 0x80000000u) ? ~u : (u | 0x80000000u);
}
__device__ inline float fdec(unsigned u){
  return __uint_as_float((u & 0x80000000u) ? (u & 0x7fffffffu) : ~u);
}
__device__ inline void zero8(float (&a)[8][8]){
  #pragma unroll
  for (int i=0;i<8;++i)
    #pragma unroll
    for (int j=0;j<8;++j) a[i][j]=0.f;
}

// stage one 128-wide k-chunk of features into act[k][row] (k-major).
// idxArr: per-row gather indices (LDS) or nullptr for identity rows rowbase+r (clamped).
__device__ inline void stage_chunk(const float* __restrict__ src, int width, int kbase,
                                   const int* idxArr, int rowbase, int limit,
                                   float (*act)[132], int t)
{
  __syncthreads();
  int k = t & 127, half = t >> 7;
  const float* sp = src + kbase + k;
  #pragma unroll
  for (int i = 0; i < 64; i += 4){
    int r = half*64 + i;
    float v[4];
    #pragma unroll
    for (int j = 0; j < 4; ++j){
      int rr = r + j;
      int g = idxArr ? idxArr[rr] : ((rowbase + rr < limit) ? (rowbase + rr) : (limit-1));
      v[j] = sp[g*width];
    }
    *(float4*)&act[k][r] = make_float4(v[0],v[1],v[2],v[3]);
  }
  __syncthreads();
}

// identity-row stage with per-column affine (x*a[k]+c[k]) applied (bnorm on the fly)
__device__ inline void stage_aff(const float* __restrict__ src, const float* __restrict__ ab,
                                 int rowbase, int limit, float (*act)[132], int t)
{
  __syncthreads();
  int k = t & 127, half = t >> 7;
  float a = ab[k], c = ab[128+k];
  const float* sp = src + k;
  #pragma unroll
  for (int i = 0; i < 64; i += 4){
    int r = half*64 + i;
    float v[4];
    #pragma unroll
    for (int j = 0; j < 4; ++j){
      int rr = r + j;
      int g = (rowbase + rr < limit) ? (rowbase + rr) : (limit-1);
      v[j] = fmaf(sp[g*128], a, c);
    }
    *(float4*)&act[k][r] = make_float4(v[0],v[1],v[2],v[3]);
  }
  __syncthreads();
}

// acc(128 rows x 128 cols, 8x8/thread) += act[0..127][rows] @ Wt[kbase+k][ccol..ccol+128)
__device__ inline void gemm128(const float* __restrict__ Wt, int ldw, int kbase, int ccol,
                               float (&acc)[8][8], float (*act)[132], float (*ws)[128], int t)
{
  int c0 = (t & 15)*8, r0 = (t >> 4)*8;
  for (int ks = 0; ks < 128; ks += 16){
    __syncthreads();
    {
      int kk = t >> 4, c = (t & 15)*8;
      const float* wp = Wt + (kbase + ks + kk)*ldw + ccol + c;
      float4 w0 = *(const float4*)wp;
      float4 w1 = *(const float4*)(wp + 4);
      *(float4*)&ws[kk][c]   = w0;
      *(float4*)&ws[kk][c+4] = w1;
    }
    __syncthreads();
    #pragma unroll
    for (int kk = 0; kk < 16; ++kk){
      int k = ks + kk;
      float4 xa = *(float4*)&act[k][r0];
      float4 xb = *(float4*)&act[k][r0+4];
      float4 wa = *(float4*)&ws[kk][c0];
      float4 wb = *(float4*)&ws[kk][c0+4];
      float x[8] = {xa.x,xa.y,xa.z,xa.w,xb.x,xb.y,xb.z,xb.w};
      float w[8] = {wa.x,wa.y,wa.z,wa.w,wb.x,wb.y,wb.z,wb.w};
      #pragma unroll
      for (int ri=0;ri<8;++ri)
        #pragma unroll
        for (int ci=0;ci<8;++ci)
          acc[ri][ci] = fmaf(x[ri], w[ci], acc[ri][ci]);
    }
  }
}

// write (acc+bias) [gelu] back into act as next layer's k-major input
__device__ inline void write_act(float (&acc)[8][8], const float* __restrict__ bias, bool doGelu,
                                 float (*act)[132], int t)
{
  int c0=(t&15)*8, r0=(t>>4)*8;
  float bv[8];
  #pragma unroll
  for (int ci=0;ci<8;++ci) bv[ci] = bias ? bias[c0+ci] : 0.f;
  __syncthreads();
  #pragma unroll
  for (int ci=0; ci<8; ++ci){
    float v[8];
    #pragma unroll
    for (int ri=0;ri<8;++ri){
      float y = acc[ri][ci] + bv[ci];
      v[ri] = doGelu ? gelu_f(y) : y;
    }
    *(float4*)&act[c0+ci][r0]   = make_float4(v[0],v[1],v[2],v[3]);
    *(float4*)&act[c0+ci][r0+4] = make_float4(v[4],v[5],v[6],v[7]);
  }
  __syncthreads();
}

__device__ inline void block_stats(const float (&ps)[8], const float (&pq)[8],
                                   float* __restrict__ stat, float* cp, int t)
{
  int c0=(t&15)*8;
  __syncthreads();
  cp[t] = 0.f;
  __syncthreads();
  #pragma unroll
  for (int ci=0;ci<8;++ci){
    atomicAdd(&cp[c0+ci], ps[ci]);
    atomicAdd(&cp[128+c0+ci], pq[ci]);
  }
  __syncthreads();
  if (t < 128){
    atomicAdd(&stat[t], cp[t]);
    atomicAdd(&stat[128+t], cp[128+t]);
  }
}

// ---------------- weight transpose ----------------
struct TP { const float* s[12]; float* d[12]; };

__global__ void kT(TP a){
  const int Os[12]={128,128,128,128,128,  4,128,512,128,128,128,128};
  const int Is[12]={256,128,128,384,128,128,128,128,512,384,128,128};
  int b = blockIdx.x, mi = 0, off = 0;
  for (;;){
    int nb = (Os[mi]*Is[mi] + 4095) >> 12;
    if (b < off + nb) break;
    off += nb; ++mi;
  }
  int O = Os[mi], I = Is[mi], sz = O*I;
  int e0 = (b - off) * 4096;
  int eEnd = (e0 + 4096 < sz) ? (e0 + 4096) : sz;
  for (int e = e0 + (int)threadIdx.x; e < eEnd; e += 256){
    int o = e / I, i = e - o*I;
    a.d[mi][i*O + o] = a.s[mi][e];
  }
}

// ---------------- kA: Bias MLP + segment max ----------------
__global__ __launch_bounds__(256,2) void kA(
    const float* __restrict__ hV, const float* __restrict__ hE, const int* __restrict__ eidx,
    const float* __restrict__ Wb1t, const float* __restrict__ Wb2t, const float* __restrict__ Wb3t,
    const float* __restrict__ bb1, const float* __restrict__ bb2, const float* __restrict__ bb3,
    float* __restrict__ wbuf, unsigned* __restrict__ mArr)
{
  __shared__ SMem sm;
  int t = threadIdx.x;
  int rowbase = blockIdx.x * 128;
  if (t < 128){
    int e = rowbase + t; if (e >= EE) e = EE-1;
    sm.idx[t]     = eidx[e];       // src
    sm.idx[128+t] = eidx[EE + e];  // dst
  }
  float acc[8][8];
  zero8(acc);
  // layer1, K=384: [hV[src] | hE | hV[dst]]
  stage_chunk(hV, 128, 0, sm.idx,      0, 0, sm.act, t);
  gemm128(Wb1t, 128, 0,   0, acc, sm.act, sm.ws, t);
  stage_chunk(hE, 128, 0, nullptr, rowbase, EE, sm.act, t);
  gemm128(Wb1t, 128, 128, 0, acc, sm.act, sm.ws, t);
  stage_chunk(hV, 128, 0, sm.idx+128,  0, 0, sm.act, t);
  gemm128(Wb1t, 128, 256, 0, acc, sm.act, sm.ws, t);
  write_act(acc, bb1, true, sm.act, t);
  zero8(acc);
  gemm128(Wb2t, 128, 0, 0, acc, sm.act, sm.ws, t);
  write_act(acc, bb2, true, sm.act, t);
  // layer3: 128 -> 4, + scale, store + atomicMax
  {
    float* w3 = &sm.ws[0][0];
    if (t < 128) ((float4*)w3)[t] = ((const float4*)Wb3t)[t];
    __syncthreads();
    for (int p = t; p < 512; p += 256){
      int row = p & 127, h = p >> 7;
      float a = 0.f;
      #pragma unroll 16
      for (int k = 0; k < 128; ++k)
        a = fmaf(sm.act[k][row], w3[k*4+h], a);
      a = (a + bb3[h]) * 0.17677669529663687f;  // 1/sqrt(32)
      int e = rowbase + row;
      if (e < EE){
        wbuf[e*4+h] = a;
        atomicMax(&mArr[(unsigned)sm.idx[row]*4 + h], fenc(a));
      }
    }
  }
}

// ---------------- kB: exp + segment sum ----------------
__global__ void kB(const int* __restrict__ eidx, const unsigned* __restrict__ mArr,
                   float* __restrict__ wbuf, float* __restrict__ sArr)
{
  int tid = blockIdx.x*256 + threadIdx.x;
  if (tid >= EE*4) return;
  int e = tid >> 2, h = tid & 3;
  int srcn = eidx[e];
  float ex = expf(wbuf[tid] - fdec(mArr[srcn*4 + h]));
  wbuf[tid] = ex;
  atomicAdd(&sArr[srcn*4 + h], ex);
}

// ---------------- kC: V MLP + weighted segment-sum aggregation ----------------
__global__ __launch_bounds__(256,2) void kC(
    const float* __restrict__ hV, const float* __restrict__ hE, const int* __restrict__ eidx,
    const float* __restrict__ Wv1t, const float* __restrict__ Wv2t, const float* __restrict__ Wv3t,
    const float* __restrict__ bv1, const float* __restrict__ bv2, const float* __restrict__ bv3,
    const float* __restrict__ wbuf, const float* __restrict__ sArr,
    float* __restrict__ agg)
{
  __shared__ SMem sm;
  int t = threadIdx.x;
  int rowbase = blockIdx.x * 128;
  if (t < 128){
    int e = rowbase + t; if (e >= EE) e = EE-1;
    sm.idx[t]     = eidx[e];
    sm.idx[128+t] = eidx[EE + e];
  }
  float acc[8][8];
  zero8(acc);
  // layer1, K=256: [hE | hV[dst]]
  stage_chunk(hE, 128, 0, nullptr, rowbase, EE, sm.act, t);
  gemm128(Wv1t, 128, 0,   0, acc, sm.act, sm.ws, t);
  stage_chunk(hV, 128, 0, sm.idx+128, 0, 0, sm.act, t);
  gemm128(Wv1t, 128, 128, 0, acc, sm.act, sm.ws, t);
  write_act(acc, bv1, true, sm.act, t);
  zero8(acc);
  gemm128(Wv2t, 128, 0, 0, acc, sm.act, sm.ws, t);
  write_act(acc, bv2, true, sm.act, t);
  zero8(acc);
  gemm128(Wv3t, 128, 0, 0, acc, sm.act, sm.ws, t);
  // epilogue: attend * V -> atomicAdd agg[src]
  int c0=(t&15)*8, r0=(t>>4)*8, h=c0>>5;
  float bv[8];
  #pragma unroll
  for (int ci=0;ci<8;++ci) bv[ci]=bv3[c0+ci];
  #pragma unroll
  for (int ri=0;ri<8;++ri){
    int row=r0+ri, e=rowbase+row;
    if (e < EE){
      int srcn = sm.idx[row];
      float attend = wbuf[e*4+h] / sArr[srcn*4+h];
      float* ap = &agg[srcn*128 + c0];
      #pragma unroll
      for (int ci=0;ci<8;++ci)
        atomicAdd(&ap[ci], attend*(acc[ri][ci]+bv[ci]));
    }
  }
}

// ---------------- kD: Wo GEMM + residual + stats0 ----------------
__global__ __launch_bounds__(256,2) void kD(
    const float* __restrict__ hV, const float* __restrict__ aggM, const float* __restrict__ Wot,
    float* __restrict__ xbuf, float* __restrict__ stat)
{
  __shared__ SMem sm;
  int t = threadIdx.x;
  int rowbase = blockIdx.x * 128;
  float acc[8][8];
  zero8(acc);
  stage_chunk(aggM, 128, 0, nullptr, rowbase, NN, sm.act, t);
  gemm128(Wot, 128, 0, 0, acc, sm.act, sm.ws, t);
  int c0=(t&15)*8, r0=(t>>4)*8;
  float ps[8]={0,0,0,0,0,0,0,0}, pq[8]={0,0,0,0,0,0,0,0};
  #pragma unroll
  for (int ri=0;ri<8;++ri){
    int g = rowbase + r0 + ri;
    if (g < NN){
      float4 h0 = *(const float4*)&hV[g*128+c0];
      float4 h1 = *(const float4*)&hV[g*128+c0+4];
      float hv[8]={h0.x,h0.y,h0.z,h0.w,h1.x,h1.y,h1.z,h1.w};
      float v[8];
      #pragma unroll
      for (int ci=0;ci<8;++ci){
        v[ci]=hv[ci]+acc[ri][ci];
        ps[ci]+=v[ci]; pq[ci]+=v[ci]*v[ci];
      }
      *(float4*)&xbuf[g*128+c0]   = make_float4(v[0],v[1],v[2],v[3]);
      *(float4*)&xbuf[g*128+c0+4] = make_float4(v[4],v[5],v[6],v[7]);
    }
  }
  block_stats(ps,pq,stat,sm.cp,t);
}

// ---------------- kFin: finalize bnorm -> (a, c) ----------------
__global__ void kFin(const float* __restrict__ stat, const float* __restrict__ gw,
                     const float* __restrict__ bw, float* __restrict__ ab, float invcnt)
{
  int t = threadIdx.x;  // 128
  float mean = stat[t]*invcnt;
  float var  = fmaxf(stat[128+t]*invcnt - mean*mean, 0.f);
  float inv  = rsqrtf(var + 1e-5f);
  float a = inv * gw[t];
  ab[t] = a;
  ab[128+t] = fmaf(-mean, a, bw[t]);
}

// ---------------- kF1: FFN layer 1 ----------------
__global__ __launch_bounds__(256,2) void kF1(
    const float* __restrict__ xbuf, const float* __restrict__ ab0,
    const float* __restrict__ Wd1t, const float* __restrict__ bd1,
    float* __restrict__ hidden)
{
  __shared__ SMem sm;
  int t = threadIdx.x;
  int rowbase = blockIdx.x * 128;
  stage_aff(xbuf, ab0, rowbase, NN, sm.act, t);
  int c0=(t&15)*8, r0=(t>>4)*8;
  for (int cc=0; cc<4; ++cc){
    float acc[8][8];
    zero8(acc);
    gemm128(Wd1t, 512, 0, cc*128, acc, sm.act, sm.ws, t);
    float bd[8];
    #pragma unroll
    for (int ci=0;ci<8;++ci) bd[ci]=bd1[cc*128+c0+ci];
    #pragma unroll
    for (int ri=0;ri<8;++ri){
      int g = rowbase + r0 + ri;
      if (g < NN){
        float v[8];
        #pragma unroll
        for (int ci=0;ci<8;++ci) v[ci]=gelu_f(acc[ri][ci]+bd[ci]);
        *(float4*)&hidden[g*512+cc*128+c0]   = make_float4(v[0],v[1],v[2],v[3]);
        *(float4*)&hidden[g*512+cc*128+c0+4] = make_float4(v[4],v[5],v[6],v[7]);
      }
    }
  }
}

// ---------------- kF2: FFN layer 2 + residual + stats1 ----------------
__global__ __launch_bounds__(256,2) void kF2(
    const float* __restrict__ xbuf, const float* __restrict__ hidden,
    const float* __restrict__ ab0, const float* __restrict__ Wd2t, const float* __restrict__ bd2,
    float* __restrict__ hVout, float* __restrict__ stat)
{
  __shared__ SMem sm;
  int t = threadIdx.x;
  int rowbase = blockIdx.x * 128;
  float acc[8][8];
  zero8(acc);
  for (int cc=0; cc<4; ++cc){
    stage_chunk(hidden, 512, cc*128, nullptr, rowbase, NN, sm.act, t);
    gemm128(Wd2t, 128, cc*128, 0, acc, sm.act, sm.ws, t);
  }
  int c0=(t&15)*8, r0=(t>>4)*8;
  float a0v[8],c0v[8],bd[8];
  #pragma unroll
  for (int ci=0;ci<8;++ci){ a0v[ci]=ab0[c0+ci]; c0v[ci]=ab0[128+c0+ci]; bd[ci]=bd2[c0+ci]; }
  float ps[8]={0,0,0,0,0,0,0,0}, pq[8]={0,0,0,0,0,0,0,0};
  #pragma unroll
  for (int ri=0;ri<8;++ri){
    int g = rowbase + r0 + ri;
    if (g < NN){
      float4 x0 = *(const float4*)&xbuf[g*128+c0];
      float4 x1 = *(const float4*)&xbuf[g*128+c0+4];
      float xv[8]={x0.x,x0.y,x0.z,x0.w,x1.x,x1.y,x1.z,x1.w};
      float v[8];
      #pragma unroll
      for (int ci=0;ci<8;++ci){
        v[ci] = fmaf(xv[ci], a0v[ci], c0v[ci]) + acc[ri][ci] + bd[ci];
        ps[ci]+=v[ci]; pq[ci]+=v[ci]*v[ci];
      }
      *(float4*)&hVout[g*128+c0]   = make_float4(v[0],v[1],v[2],v[3]);
      *(float4*)&hVout[g*128+c0+4] = make_float4(v[4],v[5],v[6],v[7]);
    }
  }
  block_stats(ps,pq,stat,sm.cp,t);
}

// ---------------- kNorm: in-place affine normalize ----------------
__global__ void kNorm(float* __restrict__ x, const float* __restrict__ ab, int total)
{
  int i = (blockIdx.x*256 + (int)threadIdx.x)*4;
  if (i >= total) return;
  float4 v = *(float4*)&x[i];
  int c = i & 127;
  v.x = fmaf(v.x, ab[c],   ab[128+c]);
  v.y = fmaf(v.y, ab[c+1], ab[128+c+1]);
  v.z = fmaf(v.z, ab[c+2], ab[128+c+2]);
  v.w = fmaf(v.w, ab[c+3], ab[128+c+3]);
  *(float4*)&x[i] = v;
}

// ---------------- kI: Edge MLP + residual + statsE ----------------
__global__ __launch_bounds__(256,2) void kI(
    const float* __restrict__ hVfin, const float* __restrict__ hE, const int* __restrict__ eidx,
    const float* __restrict__ We1t, const float* __restrict__ We2t, const float* __restrict__ We3t,
    const float* __restrict__ be1, const float* __restrict__ be2, const float* __restrict__ be3,
    float* __restrict__ hEout, float* __restrict__ stat)
{
  __shared__ SMem sm;
  int t = threadIdx.x;
  int rowbase = blockIdx.x * 128;
  if (t < 128){
    int e = rowbase + t; if (e >= EE) e = EE-1;
    sm.idx[t]     = eidx[e];
    sm.idx[128+t] = eidx[EE + e];
  }
  float acc[8][8];
  zero8(acc);
  stage_chunk(hVfin, 128, 0, sm.idx,     0, 0, sm.act, t);
  gemm128(We1t, 128, 0,   0, acc, sm.act, sm.ws, t);
  stage_chunk(hE, 128, 0, nullptr, rowbase, EE, sm.act, t);
  gemm128(We1t, 128, 128, 0, acc, sm.act, sm.ws, t);
  stage_chunk(hVfin, 128, 0, sm.idx+128, 0, 0, sm.act, t);
  gemm128(We1t, 128, 256, 0, acc, sm.act, sm.ws, t);
  write_act(acc, be1, true, sm.act, t);
  zero8(acc);
  gemm128(We2t, 128, 0, 0, acc, sm.act, sm.ws, t);
  write_act(acc, be2, true, sm.act, t);
  zero8(acc);
  gemm128(We3t, 128, 0, 0, acc, sm.act, sm.ws, t);
  // epilogue: pre = hE + msg
  int c0=(t&15)*8, r0=(t>>4)*8;
  float be[8];
  #pragma unroll
  for (int ci=0;ci<8;++ci) be[ci]=be3[c0+ci];
  float ps[8]={0,0,0,0,0,0,0,0}, pq[8]={0,0,0,0,0,0,0,0};
  #pragma unroll
  for (int ri=0;ri<8;++ri){
    int e = rowbase + r0 + ri;
    if (e < EE){
      float4 h0 = *(const float4*)&hE[e*128+c0];
      float4 h1 = *(const float4*)&hE[e*128+c0+4];
      float he[8]={h0.x,h0.y,h0.z,h0.w,h1.x,h1.y,h1.z,h1.w};
      float v[8];
      #pragma unroll
      for (int ci=0;ci<8;++ci){
        v[ci]=he[ci]+acc[ri][ci]+be[ci];
        ps[ci]+=v[ci]; pq[ci]+=v[ci]*v[ci];
      }
      *(float4*)&hEout[e*128+c0]   = make_float4(v[0],v[1],v[2],v[3]);
      *(float4*)&hEout[e*128+c0+4] = make_float4(v[4],v[5],v[6],v[7]);
    }
  }
  block_stats(ps,pq,stat,sm.cp,t);
}

// ---------------- host ----------------
extern "C" void kernel_launch(void* const* d_in, const int* in_sizes, int n_in,
                              void* d_out, int out_size, void* d_ws, size_t ws_size,
                              hipStream_t stream)
{
  const float* hV  =(const float*)d_in[0];
  const float* hE  =(const float*)d_in[1];
  const int*   eidx=(const int*)  d_in[2];
  const float* Wv1 =(const float*)d_in[4];
  const float* bv1 =(const float*)d_in[5];
  const float* Wv2 =(const float*)d_in[6];
  const float* bv2 =(const float*)d_in[7];
  const float* Wv3 =(const float*)d_in[8];
  const float* bv3 =(const float*)d_in[9];
  const float* Wb1 =(const float*)d_in[10];
  const float* bb1 =(const float*)d_in[11];
  const float* Wb2 =(const float*)d_in[12];
  const float* bb2 =(const float*)d_in[13];
  const float* Wb3 =(const float*)d_in[14];
  const float* bb3 =(const float*)d_in[15];
  const float* Wo  =(const float*)d_in[16];
  const float* g0  =(const float*)d_in[17];
  const float* b0  =(const float*)d_in[18];
  const float* g1  =(const float*)d_in[19];
  const float* b1  =(const float*)d_in[20];
  const float* Wd1 =(const float*)d_in[21];
  const float* bd1 =(const float*)d_in[22];
  const float* Wd2 =(const float*)d_in[23];
  const float* bd2 =(const float*)d_in[24];
  const float* We1 =(const float*)d_in[25];
  const float* be1 =(const float*)d_in[26];
  const float* We2 =(const float*)d_in[27];
  const float* be2 =(const float*)d_in[28];
  const float* We3 =(const float*)d_in[29];
  const float* be3 =(const float*)d_in[30];
  const float* ge  =(const float*)d_in[31];
  const float* bEn =(const float*)d_in[32];

  float* W  = (float*)d_ws;
  float* dO = (float*)d_out;

  // 1. transpose weights into ws
  TP tp;
  tp.s[0]=Wv1; tp.d[0]=W+O_Wv1t;
  tp.s[1]=Wv2; tp.d[1]=W+O_Wv2t;
  tp.s[2]=Wv3; tp.d[2]=W+O_Wv3t;
  tp.s[3]=Wb1; tp.d[3]=W+O_Wb1t;
  tp.s[4]=Wb2; tp.d[4]=W+O_Wb2t;
  tp.s[5]=Wb3; tp.d[5]=W+O_Wb3t;
  tp.s[6]=Wo;  tp.d[6]=W+O_Wot;
  tp.s[7]=Wd1; tp.d[7]=W+O_Wd1t;
  tp.s[8]=Wd2; tp.d[8]=W+O_Wd2t;
  tp.s[9]=We1; tp.d[9]=W+O_We1t;
  tp.s[10]=We2; tp.d[10]=W+O_We2t;
  tp.s[11]=We3; tp.d[11]=W+O_We3t;
  kT<<<89,256,0,stream>>>(tp);

  // 2. zero m / s / agg / stats
  hipMemsetAsync(W + O_M, 0, (size_t)(O_AB - O_M)*sizeof(float), stream);

  // 3. attention
  kA<<<(EE+127)/128,256,0,stream>>>(hV,hE,eidx, W+O_Wb1t,W+O_Wb2t,W+O_Wb3t,
                                    bb1,bb2,bb3, W+O_WB,(unsigned*)(W+O_M));
  kB<<<(EE*4+255)/256,256,0,stream>>>(eidx,(const unsigned*)(W+O_M), W+O_WB, W+O_S);
  kC<<<(EE+127)/128,256,0,stream>>>(hV,hE,eidx, W+O_Wv1t,W+O_Wv2t,W+O_Wv3t,
                                    bv1,bv2,bv3, W+O_WB, W+O_S, W+O_AGG);

  // 4. node update
  kD<<<(NN+127)/128,256,0,stream>>>(hV, W+O_AGG, W+O_Wot, W+O_XB, W+O_STAT);
  kFin<<<1,128,0,stream>>>(W+O_STAT, g0, b0, W+O_AB, 1.0f/NN);
  kF1<<<(NN+127)/128,256,0,stream>>>(W+O_XB, W+O_AB, W+O_Wd1t, bd1, W+O_HID);
  kF2<<<(NN+127)/128,256,0,stream>>>(W+O_XB, W+O_HID, W+O_AB, W+O_Wd2t, bd2,
                                     dO, W+O_STAT+256);
  kFin<<<1,128,0,stream>>>(W+O_STAT+256, g1, b1, W+O_AB+256, 1.0f/NN);
  kNorm<<<(NN*128/4+255)/256,256,0,stream>>>(dO, W+O_AB+256, NN*128);

  // 5. edge update
  kI<<<(EE+127)/128,256,0,stream>>>(dO, hE, eidx, W+O_We1t,W+O_We2t,W+O_We3t,
                                    be1,be2,be3, dO+(size_t)NN*128, W+O_STAT+512);
  kFin<<<1,128,0,stream>>>(W+O_STAT+512, ge, bEn, W+O_AB+512, 1.0f/EE);
  kNorm<<<(EE*128/4+255)/256,256,0,stream>>>(dO+(size_t)NN*128, W+O_AB+512, EE*128);
}

// Round 3
// 1922.827 us; speedup vs baseline: 2.0185x; 2.0185x over previous
//
#include <hip/hip_runtime.h>
#include <hip/hip_bf16.h>
#include <math.h>

// GeneralGNN — edge MLPs on bf16 MFMA, node path fp32 (round 2 resubmit).
//  kT    : transpose node weights (Wo, Wd1, Wd2) fp32 k-major
//  kConv : convert 9 edge-MLP weights fp32 -> bf16 row-major [O][K] (Wb3 zero-padded to 16 rows)
//  memset: zero m/s/agg/colstats
//  kA_mfma : Bias MLP per edge -> wbuf, atomicMax m[src,h]
//  kB    : wbuf = exp(w-m[src]); atomicAdd s[src,h]
//  kC_mfma : V MLP per edge; attend=wbuf/s; atomicAdd agg[src,:]
//  kD    : dh = agg@Wo^T; x = h_V+dh -> xbuf; colstats0
//  kFin/kF1/kF2/kFin/kNorm : node FFN + bnorms (fp32, unchanged)
//  kI_mfma : EdgeMLP; pre=hE+msg -> d_out[hE]; colstatsE ; kFin/kNorm

#define NN 15000
#define EE 300000

typedef short s16x8 __attribute__((ext_vector_type(8)));
typedef float f32x4 __attribute__((ext_vector_type(4)));
#define MFMA16(a,b,c) __builtin_amdgcn_mfma_f32_16x16x32_bf16((a),(b),(c),0,0,0)

// ---------- workspace layout (float offsets) ----------
#define O_Wot  0
#define O_Wd1t (O_Wot  + 128*128)
#define O_Wd2t (O_Wd1t + 128*512)
#define O_BF   (O_Wd2t + 512*128)       // bf16 weights region: 215040 ushorts = 107520 floats
#define O_WB   (O_BF + 107520)          // wbuf [E][4]
#define O_M    (O_WB + EE*4)            // m (encoded uint) [N][4]
#define O_S    (O_M + NN*4)             // s [N][4]
#define O_AGG  (O_S + NN*4)             // agg [N][128]
#define O_STAT (O_AGG + NN*128)         // 3 x (sum[128], sumsq[128])
#define O_AB   (O_STAT + 768)           // 3 x (a[128], c[128])
#define O_XB   (O_AB + 768)             // xbuf [N][128]
#define O_HID  (O_XB + NN*128)          // hidden [N][512]

// ushort offsets inside BF region
#define UB_Wb1 0
#define UB_Wb2 49152
#define UB_Wb3 65536
#define UB_Wv1 67584
#define UB_Wv2 100352
#define UB_Wv3 116736
#define UB_We1 133120
#define UB_We2 182272
#define UB_We3 198656

__device__ inline float gelu_f(float x){
  return 0.5f*x*(1.0f + erff(x*0.70710678118654752f));
}
__device__ inline unsigned fenc(float f){
  unsigned u = __float_as_uint(f);
  return (u & 0x80000000u) ? ~u : (u | 0x80000000u);
}
__device__ inline float fdec(unsigned u){
  return __uint_as_float((u & 0x80000000u) ? (u & 0x7fffffffu) : ~u);
}
__device__ inline ushort bfb(float f){
  __bf16 h = (__bf16)f;
  return __builtin_bit_cast(unsigned short, h);
}

// ================= MFMA edge-MLP machinery =================
// Orientation: D' = W (A, M=outcols) x X^T (B, N=edges).
// A-frag: lane reads W[wm*64+mt*16+(l&15)][kt*32+(l>>4)*8 .. +8] (bf16 row-major, global/L2)
// B-frag: lane reads X[edge][same k range] (8 fp32 -> cvt)
// C/D  : lane holds edge=(l&15), outcols (l>>4)*4+0..3  -> short4 LDS store is contiguous.

struct EMem {
  ushort act[128][128];   // inter-layer activations, XOR-swizzled (32 KB)
  int   idx[256];         // src[128], dst[128]
  float cp[256];          // column stat partials
};

union FB { s16x8 v; ushort u[8]; };

__device__ inline s16x8 load_x8(const float* __restrict__ p){
  float4 a = *(const float4*)p;
  float4 b = *(const float4*)(p+4);
  FB r;
  r.u[0]=bfb(a.x); r.u[1]=bfb(a.y); r.u[2]=bfb(a.z); r.u[3]=bfb(a.w);
  r.u[4]=bfb(b.x); r.u[5]=bfb(b.y); r.u[6]=bfb(b.z); r.u[7]=bfb(b.w);
  return r.v;
}

// XOR swizzle: permute 8-elem (16B) blocks within a row by row&7 (proven fix, G4)
__device__ inline void st_act4(ushort (*act)[128], int e, int obase,
                               float g0,float g1,float g2,float g3){
  short4 s;
  s.x=(short)bfb(g0); s.y=(short)bfb(g1); s.z=(short)bfb(g2); s.w=(short)bfb(g3);
  *(short4*)&act[e][obase ^ ((e&7)<<3)] = s;
}
__device__ inline s16x8 ld_act(ushort (*act)[128], int e, int k0){
  return *(const s16x8*)&act[e][k0 ^ ((e&7)<<3)];
}

__device__ inline void zacc(f32x4 (&a)[4][4]){
  #pragma unroll
  for(int i=0;i<4;++i)
    #pragma unroll
    for(int j=0;j<4;++j) a[i][j] = (f32x4){0.f,0.f,0.f,0.f};
}

// K=128 layer from LDS activations: acc += W x act^T
__device__ inline void mm_lds(const ushort* __restrict__ Wb, ushort (*act)[128],
                              int wm, int wn, int el, int kq, f32x4 (&acc)[4][4])
{
  #pragma unroll
  for (int kt=0; kt<4; ++kt){
    s16x8 af[4], bfr[4];
    #pragma unroll
    for (int mt=0;mt<4;++mt)
      af[mt] = *(const s16x8*)&Wb[(wm*64+mt*16+el)*128 + kt*32 + kq*8];
    #pragma unroll
    for (int nt=0;nt<4;++nt)
      bfr[nt] = ld_act(act, wn*64+nt*16+el, kt*32+kq*8);
    #pragma unroll
    for (int mt=0;mt<4;++mt)
      #pragma unroll
      for (int nt=0;nt<4;++nt)
        acc[mt][nt] = MFMA16(af[mt], bfr[nt], acc[mt][nt]);
  }
}

// bias + gelu + store to LDS act (next layer's input)
__device__ inline void intf(f32x4 (&acc)[4][4], const float* __restrict__ bias,
                            ushort (*act)[128], int wm, int wn, int el, int kq)
{
  #pragma unroll
  for (int mt=0;mt<4;++mt){
    int obase = wm*64+mt*16+kq*4;
    float4 bb = *(const float4*)&bias[obase];
    #pragma unroll
    for (int nt=0;nt<4;++nt){
      int e = wn*64+nt*16+el;
      st_act4(act, e, obase,
        gelu_f(acc[mt][nt][0]+bb.x), gelu_f(acc[mt][nt][1]+bb.y),
        gelu_f(acc[mt][nt][2]+bb.z), gelu_f(acc[mt][nt][3]+bb.w));
    }
  }
}

// layer1 with 3 segments [gather g0 | identity gi | gather g2], K=384
__device__ inline void edge_l1_3seg(const float* __restrict__ gV, const float* __restrict__ gI,
    const int* idx, const ushort* __restrict__ W1, int rowbase,
    int wm, int wn, int el, int kq, f32x4 (&acc)[4][4])
{
  #pragma unroll
  for (int seg=0; seg<3; ++seg){
    const float* rp[4];
    #pragma unroll
    for (int nt=0; nt<4; ++nt){
      int eloc = wn*64+nt*16+el;
      int g;
      if (seg==0) g = idx[eloc];
      else if (seg==1){ int e=rowbase+eloc; g = (e<EE)?e:(EE-1); }
      else g = idx[128+eloc];
      rp[nt] = ((seg==1)?gI:gV) + (size_t)g*128 + kq*8;
    }
    #pragma unroll
    for (int kt=0; kt<4; ++kt){
      s16x8 af[4], bfr[4];
      #pragma unroll
      for (int mt=0;mt<4;++mt)
        af[mt] = *(const s16x8*)&W1[(wm*64+mt*16+el)*384 + seg*128 + kt*32 + kq*8];
      #pragma unroll
      for (int nt=0;nt<4;++nt)
        bfr[nt] = load_x8(rp[nt] + kt*32);
      #pragma unroll
      for (int mt=0;mt<4;++mt)
        #pragma unroll
        for (int nt=0;nt<4;++nt)
          acc[mt][nt] = MFMA16(af[mt], bfr[nt], acc[mt][nt]);
    }
  }
}

// ---------------- kA: Bias MLP + segment max ----------------
__global__ void kA_mfma(const float* __restrict__ hV, const float* __restrict__ hE,
    const int* __restrict__ eidx,
    const ushort* __restrict__ W1, const ushort* __restrict__ W2, const ushort* __restrict__ W3,
    const float* __restrict__ b1, const float* __restrict__ b2, const float* __restrict__ b3,
    float* __restrict__ wbuf, unsigned* __restrict__ mArr)
{
  __shared__ EMem sm;
  int t = threadIdx.x, lane = t&63, wave = t>>6;
  int el = lane&15, kq = lane>>4, wm = wave>>1, wn = wave&1;
  int rowbase = blockIdx.x*128;
  if (t<128){ int e=rowbase+t; if(e>=EE) e=EE-1; sm.idx[t]=eidx[e]; sm.idx[128+t]=eidx[EE+e]; }
  __syncthreads();
  f32x4 acc[4][4]; zacc(acc);
  edge_l1_3seg(hV, hE, sm.idx, W1, rowbase, wm, wn, el, kq, acc);
  intf(acc, b1, sm.act, wm, wn, el, kq);
  __syncthreads();
  zacc(acc);
  mm_lds(W2, sm.act, wm, wn, el, kq, acc);
  __syncthreads();
  intf(acc, b2, sm.act, wm, wn, el, kq);
  __syncthreads();
  // L3: 128 -> 4 heads (W3 zero-padded to 16 rows); each wave: edges wave*32..+31
  f32x4 a3[2]; a3[0]=(f32x4){0.f,0.f,0.f,0.f}; a3[1]=(f32x4){0.f,0.f,0.f,0.f};
  #pragma unroll
  for (int kt=0;kt<4;++kt){
    s16x8 af = *(const s16x8*)&W3[el*128 + kt*32 + kq*8];
    #pragma unroll
    for (int q=0;q<2;++q){
      s16x8 bv = ld_act(sm.act, wave*32+q*16+el, kt*32+kq*8);
      a3[q] = MFMA16(af, bv, a3[q]);
    }
  }
  if (kq==0){
    #pragma unroll
    for (int q=0;q<2;++q){
      int eloc = wave*32+q*16+el, e = rowbase+eloc;
      if (e<EE){
        const float SC = 0.17677669529663687f;  // 1/sqrt(32)
        float4 w;
        w.x=(a3[q][0]+b3[0])*SC; w.y=(a3[q][1]+b3[1])*SC;
        w.z=(a3[q][2]+b3[2])*SC; w.w=(a3[q][3]+b3[3])*SC;
        *(float4*)&wbuf[e*4] = w;
        unsigned s4 = (unsigned)sm.idx[eloc]*4;
        atomicMax(&mArr[s4+0],fenc(w.x));
        atomicMax(&mArr[s4+1],fenc(w.y));
        atomicMax(&mArr[s4+2],fenc(w.z));
        atomicMax(&mArr[s4+3],fenc(w.w));
      }
    }
  }
}

// ---------------- kB: exp + segment sum ----------------
__global__ void kB(const int* __restrict__ eidx, const unsigned* __restrict__ mArr,
                   float* __restrict__ wbuf, float* __restrict__ sArr)
{
  int tid = blockIdx.x*256 + threadIdx.x;
  if (tid >= EE*4) return;
  int e = tid >> 2, h = tid & 3;
  int srcn = eidx[e];
  float ex = expf(wbuf[tid] - fdec(mArr[srcn*4 + h]));
  wbuf[tid] = ex;
  atomicAdd(&sArr[srcn*4 + h], ex);
}

// ---------------- kC: V MLP + weighted aggregation ----------------
__global__ void kC_mfma(const float* __restrict__ hV, const float* __restrict__ hE,
    const int* __restrict__ eidx,
    const ushort* __restrict__ W1, const ushort* __restrict__ W2, const ushort* __restrict__ W3,
    const float* __restrict__ b1, const float* __restrict__ b2, const float* __restrict__ b3,
    const float* __restrict__ wbuf, const float* __restrict__ sArr,
    float* __restrict__ agg)
{
  __shared__ EMem sm;
  int t = threadIdx.x, lane = t&63, wave = t>>6;
  int el = lane&15, kq = lane>>4, wm = wave>>1, wn = wave&1;
  int rowbase = blockIdx.x*128;
  if (t<128){ int e=rowbase+t; if(e>=EE) e=EE-1; sm.idx[t]=eidx[e]; sm.idx[128+t]=eidx[EE+e]; }
  __syncthreads();
  f32x4 acc[4][4]; zacc(acc);
  // layer1 K=256: [hE identity | hV gather dst]
  #pragma unroll
  for (int seg=0; seg<2; ++seg){
    const float* rp[4];
    #pragma unroll
    for (int nt=0; nt<4; ++nt){
      int eloc = wn*64+nt*16+el;
      int g;
      if (seg==0){ int e=rowbase+eloc; g = (e<EE)?e:(EE-1); }
      else g = sm.idx[128+eloc];
      rp[nt] = ((seg==0)?hE:hV) + (size_t)g*128 + kq*8;
    }
    #pragma unroll
    for (int kt=0; kt<4; ++kt){
      s16x8 af[4], bfr[4];
      #pragma unroll
      for (int mt=0;mt<4;++mt)
        af[mt] = *(const s16x8*)&W1[(wm*64+mt*16+el)*256 + seg*128 + kt*32 + kq*8];
      #pragma unroll
      for (int nt=0;nt<4;++nt)
        bfr[nt] = load_x8(rp[nt] + kt*32);
      #pragma unroll
      for (int mt=0;mt<4;++mt)
        #pragma unroll
        for (int nt=0;nt<4;++nt)
          acc[mt][nt] = MFMA16(af[mt], bfr[nt], acc[mt][nt]);
    }
  }
  intf(acc, b1, sm.act, wm, wn, el, kq);
  __syncthreads();
  zacc(acc);
  mm_lds(W2, sm.act, wm, wn, el, kq, acc);
  __syncthreads();
  intf(acc, b2, sm.act, wm, wn, el, kq);
  __syncthreads();
  zacc(acc);
  mm_lds(W3, sm.act, wm, wn, el, kq, acc);
  // epilogue: attend * V -> atomicAdd agg[src]
  #pragma unroll
  for (int nt=0;nt<4;++nt){
    int eloc = wn*64+nt*16+el, e = rowbase+eloc;
    if (e < EE){
      int sn = sm.idx[eloc];
      float4 wv = *(const float4*)&wbuf[e*4];
      float4 sv = *(const float4*)&sArr[sn*4];
      float at4[4] = {wv.x/sv.x, wv.y/sv.y, wv.z/sv.z, wv.w/sv.w};
      #pragma unroll
      for (int mt=0;mt<4;++mt){
        int o = wm*64+mt*16+kq*4;
        float4 bb = *(const float4*)&b3[o];
        float a = at4[o>>5];
        float* ap = &agg[(size_t)sn*128 + o];
        atomicAdd(ap+0, a*(acc[mt][nt][0]+bb.x));
        atomicAdd(ap+1, a*(acc[mt][nt][1]+bb.y));
        atomicAdd(ap+2, a*(acc[mt][nt][2]+bb.z));
        atomicAdd(ap+3, a*(acc[mt][nt][3]+bb.w));
      }
    }
  }
}

// ---------------- kI: Edge MLP + residual + statsE ----------------
__global__ void kI_mfma(const float* __restrict__ hVfin, const float* __restrict__ hE,
    const int* __restrict__ eidx,
    const ushort* __restrict__ W1, const ushort* __restrict__ W2, const ushort* __restrict__ W3,
    const float* __restrict__ b1, const float* __restrict__ b2, const float* __restrict__ b3,
    float* __restrict__ hEout, float* __restrict__ stat)
{
  __shared__ EMem sm;
  int t = threadIdx.x, lane = t&63, wave = t>>6;
  int el = lane&15, kq = lane>>4, wm = wave>>1, wn = wave&1;
  int rowbase = blockIdx.x*128;
  if (t<128){ int e=rowbase+t; if(e>=EE) e=EE-1; sm.idx[t]=eidx[e]; sm.idx[128+t]=eidx[EE+e]; }
  __syncthreads();
  f32x4 acc[4][4]; zacc(acc);
  edge_l1_3seg(hVfin, hE, sm.idx, W1, rowbase, wm, wn, el, kq, acc);
  intf(acc, b1, sm.act, wm, wn, el, kq);
  __syncthreads();
  zacc(acc);
  mm_lds(W2, sm.act, wm, wn, el, kq, acc);
  __syncthreads();
  intf(acc, b2, sm.act, wm, wn, el, kq);
  __syncthreads();
  zacc(acc);
  mm_lds(W3, sm.act, wm, wn, el, kq, acc);
  // epilogue: pre = hE + msg + b3 ; stats
  float ps[4][4], pq[4][4];
  #pragma unroll
  for (int mt=0;mt<4;++mt)
    #pragma unroll
    for (int r=0;r<4;++r){ ps[mt][r]=0.f; pq[mt][r]=0.f; }
  #pragma unroll
  for (int nt=0;nt<4;++nt){
    int eloc = wn*64+nt*16+el, e = rowbase+eloc;
    if (e < EE){
      #pragma unroll
      for (int mt=0;mt<4;++mt){
        int o = wm*64+mt*16+kq*4;
        float4 bb = *(const float4*)&b3[o];
        float4 h0 = *(const float4*)&hE[(size_t)e*128+o];
        float4 v;
        v.x = h0.x+acc[mt][nt][0]+bb.x;
        v.y = h0.y+acc[mt][nt][1]+bb.y;
        v.z = h0.z+acc[mt][nt][2]+bb.z;
        v.w = h0.w+acc[mt][nt][3]+bb.w;
        *(float4*)&hEout[(size_t)e*128+o] = v;
        ps[mt][0]+=v.x; ps[mt][1]+=v.y; ps[mt][2]+=v.z; ps[mt][3]+=v.w;
        pq[mt][0]+=v.x*v.x; pq[mt][1]+=v.y*v.y; pq[mt][2]+=v.z*v.z; pq[mt][3]+=v.w*v.w;
      }
    }
  }
  __syncthreads();
  sm.cp[t] = 0.f;
  __syncthreads();
  #pragma unroll
  for (int mt=0;mt<4;++mt){
    int o = wm*64+mt*16+kq*4;
    #pragma unroll
    for (int r=0;r<4;++r){
      atomicAdd(&sm.cp[o+r], ps[mt][r]);
      atomicAdd(&sm.cp[128+o+r], pq[mt][r]);
    }
  }
  __syncthreads();
  atomicAdd(&stat[t], sm.cp[t]);
}

// ================= fp32 node path (unchanged machinery) =================
struct SMem {
  float act[128][132];
  float ws[16][128];
  int   idx[256];
  float cp[256];
};

__device__ inline void zero8(float (&a)[8][8]){
  #pragma unroll
  for (int i=0;i<8;++i)
    #pragma unroll
    for (int j=0;j<8;++j) a[i][j]=0.f;
}

__device__ inline void stage_chunk(const float* __restrict__ src, int width, int kbase,
                                   const int* idxArr, int rowbase, int limit,
                                   float (*act)[132], int t)
{
  __syncthreads();
  int k = t & 127, half = t >> 7;
  const float* sp = src + kbase + k;
  #pragma unroll
  for (int i = 0; i < 64; i += 4){
    int r = half*64 + i;
    float v[4];
    #pragma unroll
    for (int j = 0; j < 4; ++j){
      int rr = r + j;
      int g = idxArr ? idxArr[rr] : ((rowbase + rr < limit) ? (rowbase + rr) : (limit-1));
      v[j] = sp[g*width];
    }
    *(float4*)&act[k][r] = make_float4(v[0],v[1],v[2],v[3]);
  }
  __syncthreads();
}

__device__ inline void stage_aff(const float* __restrict__ src, const float* __restrict__ ab,
                                 int rowbase, int limit, float (*act)[132], int t)
{
  __syncthreads();
  int k = t & 127, half = t >> 7;
  float a = ab[k], c = ab[128+k];
  const float* sp = src + k;
  #pragma unroll
  for (int i = 0; i < 64; i += 4){
    int r = half*64 + i;
    float v[4];
    #pragma unroll
    for (int j = 0; j < 4; ++j){
      int rr = r + j;
      int g = (rowbase + rr < limit) ? (rowbase + rr) : (limit-1);
      v[j] = fmaf(sp[g*128], a, c);
    }
    *(float4*)&act[k][r] = make_float4(v[0],v[1],v[2],v[3]);
  }
  __syncthreads();
}

__device__ inline void gemm128(const float* __restrict__ Wt, int ldw, int kbase, int ccol,
                               float (&acc)[8][8], float (*act)[132], float (*ws)[128], int t)
{
  int c0 = (t & 15)*8, r0 = (t >> 4)*8;
  for (int ks = 0; ks < 128; ks += 16){
    __syncthreads();
    {
      int kk = t >> 4, c = (t & 15)*8;
      const float* wp = Wt + (kbase + ks + kk)*ldw + ccol + c;
      float4 w0 = *(const float4*)wp;
      float4 w1 = *(const float4*)(wp + 4);
      *(float4*)&ws[kk][c]   = w0;
      *(float4*)&ws[kk][c+4] = w1;
    }
    __syncthreads();
    #pragma unroll
    for (int kk = 0; kk < 16; ++kk){
      int k = ks + kk;
      float4 xa = *(float4*)&act[k][r0];
      float4 xb = *(float4*)&act[k][r0+4];
      float4 wa = *(float4*)&ws[kk][c0];
      float4 wb = *(float4*)&ws[kk][c0+4];
      float x[8] = {xa.x,xa.y,xa.z,xa.w,xb.x,xb.y,xb.z,xb.w};
      float w[8] = {wa.x,wa.y,wa.z,wa.w,wb.x,wb.y,wb.z,wb.w};
      #pragma unroll
      for (int ri=0;ri<8;++ri)
        #pragma unroll
        for (int ci=0;ci<8;++ci)
          acc[ri][ci] = fmaf(x[ri], w[ci], acc[ri][ci]);
    }
  }
}

__device__ inline void block_stats(const float (&ps)[8], const float (&pq)[8],
                                   float* __restrict__ stat, float* cp, int t)
{
  int c0=(t&15)*8;
  __syncthreads();
  cp[t] = 0.f;
  __syncthreads();
  #pragma unroll
  for (int ci=0;ci<8;++ci){
    atomicAdd(&cp[c0+ci], ps[ci]);
    atomicAdd(&cp[128+c0+ci], pq[ci]);
  }
  __syncthreads();
  if (t < 128){
    atomicAdd(&stat[t], cp[t]);
    atomicAdd(&stat[128+t], cp[128+t]);
  }
}

// ---------------- weight prep ----------------
struct TP { const float* s[3]; float* d[3]; };

__global__ void kT(TP a){
  const int Os[3]={128,512,128};
  const int Is[3]={128,128,512};
  int b = blockIdx.x, mi = 0, off = 0;
  for (;;){
    int nb = (Os[mi]*Is[mi] + 4095) >> 12;
    if (b < off + nb) break;
    off += nb; ++mi;
  }
  int O = Os[mi], I = Is[mi], sz = O*I;
  int e0 = (b - off) * 4096;
  int eEnd = (e0 + 4096 < sz) ? (e0 + 4096) : sz;
  for (int e = e0 + (int)threadIdx.x; e < eEnd; e += 256){
    int o = e / I, i = e - o*I;
    a.d[mi][i*O + o] = a.s[mi][e];
  }
}

struct CP9 { const float* s[9]; };

__global__ void kConv(CP9 a, ushort* __restrict__ dst){
  const int SZ[9]   = {49152,16384,2048,32768,16384,16384,49152,16384,16384};
  const int SRCSZ[9]= {49152,16384, 512,32768,16384,16384,49152,16384,16384};
  int b = blockIdx.x, mi=0, off=0;
  for(;;){ int nb=(SZ[mi]+1023)>>10; if (b<off+nb) break; off+=nb; ++mi; }
  int base=0;
  for(int j=0;j<mi;++j) base+=SZ[j];
  int e0=(b-off)*1024;
  int eE=(e0+1024<SZ[mi])?(e0+1024):SZ[mi];
  for (int i=e0+(int)threadIdx.x; i<eE; i+=256){
    float v = (i < SRCSZ[mi]) ? a.s[mi][i] : 0.f;
    dst[base+i] = bfb(v);
  }
}

// ---------------- kD: Wo GEMM + residual + stats0 ----------------
__global__ __launch_bounds__(256,2) void kD(
    const float* __restrict__ hV, const float* __restrict__ aggM, const float* __restrict__ Wot,
    float* __restrict__ xbuf, float* __restrict__ stat)
{
  __shared__ SMem sm;
  int t = threadIdx.x;
  int rowbase = blockIdx.x * 128;
  float acc[8][8];
  zero8(acc);
  stage_chunk(aggM, 128, 0, nullptr, rowbase, NN, sm.act, t);
  gemm128(Wot, 128, 0, 0, acc, sm.act, sm.ws, t);
  int c0=(t&15)*8, r0=(t>>4)*8;
  float ps[8]={0,0,0,0,0,0,0,0}, pq[8]={0,0,0,0,0,0,0,0};
  #pragma unroll
  for (int ri=0;ri<8;++ri){
    int g = rowbase + r0 + ri;
    if (g < NN){
      float4 h0 = *(const float4*)&hV[g*128+c0];
      float4 h1 = *(const float4*)&hV[g*128+c0+4];
      float hv[8]={h0.x,h0.y,h0.z,h0.w,h1.x,h1.y,h1.z,h1.w};
      float v[8];
      #pragma unroll
      for (int ci=0;ci<8;++ci){
        v[ci]=hv[ci]+acc[ri][ci];
        ps[ci]+=v[ci]; pq[ci]+=v[ci]*v[ci];
      }
      *(float4*)&xbuf[g*128+c0]   = make_float4(v[0],v[1],v[2],v[3]);
      *(float4*)&xbuf[g*128+c0+4] = make_float4(v[4],v[5],v[6],v[7]);
    }
  }
  block_stats(ps,pq,stat,sm.cp,t);
}

// ---------------- kFin ----------------
__global__ void kFin(const float* __restrict__ stat, const float* __restrict__ gw,
                     const float* __restrict__ bw, float* __restrict__ ab, float invcnt)
{
  int t = threadIdx.x;  // 128
  float mean = stat[t]*invcnt;
  float var  = fmaxf(stat[128+t]*invcnt - mean*mean, 0.f);
  float inv  = rsqrtf(var + 1e-5f);
  float a = inv * gw[t];
  ab[t] = a;
  ab[128+t] = fmaf(-mean, a, bw[t]);
}

// ---------------- kF1 ----------------
__global__ __launch_bounds__(256,2) void kF1(
    const float* __restrict__ xbuf, const float* __restrict__ ab0,
    const float* __restrict__ Wd1t, const float* __restrict__ bd1,
    float* __restrict__ hidden)
{
  __shared__ SMem sm;
  int t = threadIdx.x;
  int rowbase = blockIdx.x * 128;
  stage_aff(xbuf, ab0, rowbase, NN, sm.act, t);
  int c0=(t&15)*8, r0=(t>>4)*8;
  for (int cc=0; cc<4; ++cc){
    float acc[8][8];
    zero8(acc);
    gemm128(Wd1t, 512, 0, cc*128, acc, sm.act, sm.ws, t);
    float bd[8];
    #pragma unroll
    for (int ci=0;ci<8;++ci) bd[ci]=bd1[cc*128+c0+ci];
    #pragma unroll
    for (int ri=0;ri<8;++ri){
      int g = rowbase + r0 + ri;
      if (g < NN){
        float v[8];
        #pragma unroll
        for (int ci=0;ci<8;++ci) v[ci]=gelu_f(acc[ri][ci]+bd[ci]);
        *(float4*)&hidden[g*512+cc*128+c0]   = make_float4(v[0],v[1],v[2],v[3]);
        *(float4*)&hidden[g*512+cc*128+c0+4] = make_float4(v[4],v[5],v[6],v[7]);
      }
    }
  }
}

// ---------------- kF2 ----------------
__global__ __launch_bounds__(256,2) void kF2(
    const float* __restrict__ xbuf, const float* __restrict__ hidden,
    const float* __restrict__ ab0, const float* __restrict__ Wd2t, const float* __restrict__ bd2,
    float* __restrict__ hVout, float* __restrict__ stat)
{
  __shared__ SMem sm;
  int t = threadIdx.x;
  int rowbase = blockIdx.x * 128;
  float acc[8][8];
  zero8(acc);
  for (int cc=0; cc<4; ++cc){
    stage_chunk(hidden, 512, cc*128, nullptr, rowbase, NN, sm.act, t);
    gemm128(Wd2t, 128, cc*128, 0, acc, sm.act, sm.ws, t);
  }
  int c0=(t&15)*8, r0=(t>>4)*8;
  float a0v[8],c0v[8],bd[8];
  #pragma unroll
  for (int ci=0;ci<8;++ci){ a0v[ci]=ab0[c0+ci]; c0v[ci]=ab0[128+c0+ci]; bd[ci]=bd2[c0+ci]; }
  float ps[8]={0,0,0,0,0,0,0,0}, pq[8]={0,0,0,0,0,0,0,0};
  #pragma unroll
  for (int ri=0;ri<8;++ri){
    int g = rowbase + r0 + ri;
    if (g < NN){
      float4 x0 = *(const float4*)&xbuf[g*128+c0];
      float4 x1 = *(const float4*)&xbuf[g*128+c0+4];
      float xv[8]={x0.x,x0.y,x0.z,x0.w,x1.x,x1.y,x1.z,x1.w};
      float v[8];
      #pragma unroll
      for (int ci=0;ci<8;++ci){
        v[ci] = fmaf(xv[ci], a0v[ci], c0v[ci]) + acc[ri][ci] + bd[ci];
        ps[ci]+=v[ci]; pq[ci]+=v[ci]*v[ci];
      }
      *(float4*)&hVout[g*128+c0]   = make_float4(v[0],v[1],v[2],v[3]);
      *(float4*)&hVout[g*128+c0+4] = make_float4(v[4],v[5],v[6],v[7]);
    }
  }
  block_stats(ps,pq,stat,sm.cp,t);
}

// ---------------- kNorm ----------------
__global__ void kNorm(float* __restrict__ x, const float* __restrict__ ab, int total)
{
  int i = (blockIdx.x*256 + (int)threadIdx.x)*4;
  if (i >= total) return;
  float4 v = *(float4*)&x[i];
  int c = i & 127;
  v.x = fmaf(v.x, ab[c],   ab[128+c]);
  v.y = fmaf(v.y, ab[c+1], ab[128+c+1]);
  v.z = fmaf(v.z, ab[c+2], ab[128+c+2]);
  v.w = fmaf(v.w, ab[c+3], ab[128+c+3]);
  *(float4*)&x[i] = v;
}

// ---------------- host ----------------
extern "C" void kernel_launch(void* const* d_in, const int* in_sizes, int n_in,
                              void* d_out, int out_size, void* d_ws, size_t ws_size,
                              hipStream_t stream)
{
  const float* hV  =(const float*)d_in[0];
  const float* hE  =(const float*)d_in[1];
  const int*   eidx=(const int*)  d_in[2];
  const float* Wv1 =(const float*)d_in[4];
  const float* bv1 =(const float*)d_in[5];
  const float* Wv2 =(const float*)d_in[6];
  const float* bv2 =(const float*)d_in[7];
  const float* Wv3 =(const float*)d_in[8];
  const float* bv3 =(const float*)d_in[9];
  const float* Wb1 =(const float*)d_in[10];
  const float* bb1 =(const float*)d_in[11];
  const float* Wb2 =(const float*)d_in[12];
  const float* bb2 =(const float*)d_in[13];
  const float* Wb3 =(const float*)d_in[14];
  const float* bb3 =(const float*)d_in[15];
  const float* Wo  =(const float*)d_in[16];
  const float* g0  =(const float*)d_in[17];
  const float* b0  =(const float*)d_in[18];
  const float* g1  =(const float*)d_in[19];
  const float* b1  =(const float*)d_in[20];
  const float* Wd1 =(const float*)d_in[21];
  const float* bd1 =(const float*)d_in[22];
  const float* Wd2 =(const float*)d_in[23];
  const float* bd2 =(const float*)d_in[24];
  const float* We1 =(const float*)d_in[25];
  const float* be1 =(const float*)d_in[26];
  const float* We2 =(const float*)d_in[27];
  const float* be2 =(const float*)d_in[28];
  const float* We3 =(const float*)d_in[29];
  const float* be3 =(const float*)d_in[30];
  const float* ge  =(const float*)d_in[31];
  const float* bEn =(const float*)d_in[32];

  float* W  = (float*)d_ws;
  float* dO = (float*)d_out;
  ushort* WB = (ushort*)(W + O_BF);

  // 1. node weights fp32 transpose
  TP tp;
  tp.s[0]=Wo;  tp.d[0]=W+O_Wot;
  tp.s[1]=Wd1; tp.d[1]=W+O_Wd1t;
  tp.s[2]=Wd2; tp.d[2]=W+O_Wd2t;
  kT<<<36,256,0,stream>>>(tp);

  // 2. edge weights -> bf16 (row-major [O][K])
  CP9 c9;
  c9.s[0]=Wb1; c9.s[1]=Wb2; c9.s[2]=Wb3;
  c9.s[3]=Wv1; c9.s[4]=Wv2; c9.s[5]=Wv3;
  c9.s[6]=We1; c9.s[7]=We2; c9.s[8]=We3;
  kConv<<<210,256,0,stream>>>(c9, WB);

  // 3. zero m / s / agg / stats
  hipMemsetAsync(W + O_M, 0, (size_t)(O_AB - O_M)*sizeof(float), stream);

  // 4. attention
  kA_mfma<<<(EE+127)/128,256,0,stream>>>(hV,hE,eidx, WB+UB_Wb1,WB+UB_Wb2,WB+UB_Wb3,
                                         bb1,bb2,bb3, W+O_WB,(unsigned*)(W+O_M));
  kB<<<(EE*4+255)/256,256,0,stream>>>(eidx,(const unsigned*)(W+O_M), W+O_WB, W+O_S);
  kC_mfma<<<(EE+127)/128,256,0,stream>>>(hV,hE,eidx, WB+UB_Wv1,WB+UB_Wv2,WB+UB_Wv3,
                                         bv1,bv2,bv3, W+O_WB, W+O_S, W+O_AGG);

  // 5. node update (fp32)
  kD<<<(NN+127)/128,256,0,stream>>>(hV, W+O_AGG, W+O_Wot, W+O_XB, W+O_STAT);
  kFin<<<1,128,0,stream>>>(W+O_STAT, g0, b0, W+O_AB, 1.0f/NN);
  kF1<<<(NN+127)/128,256,0,stream>>>(W+O_XB, W+O_AB, W+O_Wd1t, bd1, W+O_HID);
  kF2<<<(NN+127)/128,256,0,stream>>>(W+O_XB, W+O_HID, W+O_AB, W+O_Wd2t, bd2,
                                     dO, W+O_STAT+256);
  kFin<<<1,128,0,stream>>>(W+O_STAT+256, g1, b1, W+O_AB+256, 1.0f/NN);
  kNorm<<<(NN*128/4+255)/256,256,0,stream>>>(dO, W+O_AB+256, NN*128);

  // 6. edge update (bf16 MFMA)
  kI_mfma<<<(EE+127)/128,256,0,stream>>>(dO, hE, eidx, WB+UB_We1,WB+UB_We2,WB+UB_We3,
                                         be1,be2,be3, dO+(size_t)NN*128, W+O_STAT+512);
  kFin<<<1,128,0,stream>>>(W+O_STAT+512, ge, bEn, W+O_AB+512, 1.0f/EE);
  kNorm<<<(EE*128/4+255)/256,256,0,stream>>>(dO+(size_t)NN*128, W+O_AB+512, EE*128);
}

// Round 5
// 1641.610 us; speedup vs baseline: 2.3643x; 1.1713x over previous
//
#include <hip/hip_runtime.h>
#include <hip/hip_bf16.h>
#include <math.h>

// GeneralGNN — edge MLPs on bf16 MFMA; kC uses src-sorted edges + LDS
// segmented reduction instead of 38M global atomics (round 3 resubmit).
//  kT    : transpose node weights (Wo, Wd1, Wd2) fp32 k-major
//  kConv : convert 9 edge-MLP weights fp32 -> bf16 row-major [O][K]
//  kHist/kScan/kScat : counting sort of edges by src -> perm
//  kA_mfma : Bias MLP per edge -> wbuf, atomicMax m[src,h]
//  kB    : wbuf = exp(w-m[src]); atomicAdd s[src,h]
//  kC_mfma : V MLP on sorted edges; attend*V -> LDS segmented reduce -> few atomics
//  kD/kFin/kF1/kF2/kFin/kNorm : node path (fp32, unchanged)
//  kI_mfma : EdgeMLP; pre=hE+msg -> d_out[hE]; statsE ; kFin/kNorm

#define NN 15000
#define EE 300000

typedef short s16x8 __attribute__((ext_vector_type(8)));
typedef float f32x4 __attribute__((ext_vector_type(4)));
#define MFMA16(a,b,c) __builtin_amdgcn_mfma_f32_16x16x32_bf16((a),(b),(c),0,0,0)

// ---------- workspace layout (float offsets) ----------
#define O_Wot  0
#define O_Wd1t (O_Wot  + 128*128)
#define O_Wd2t (O_Wd1t + 128*512)
#define O_BF   (O_Wd2t + 512*128)       // bf16 weights region: 215040 ushorts
#define O_WB   (O_BF + 107520)          // wbuf [E][4]
#define O_M    (O_WB + EE*4)            // m (encoded uint) [N][4]
#define O_S    (O_M + NN*4)             // s [N][4]
#define O_AGG  (O_S + NN*4)             // agg [N][128]
#define O_STAT (O_AGG + NN*128)         // 3 x (sum[128], sumsq[128])
#define O_AB   (O_STAT + 768)           // 3 x (a[128], c[128])
#define O_XB   (O_AB + 768)             // xbuf [N][128]
#define O_HID  (O_XB + NN*128)          // hidden [N][512]
#define O_PERM (O_HID + NN*512)         // perm [E] (int)
#define O_CNT  (O_PERM + EE)            // cnt [15360] (int)
#define O_CUR  (O_CNT + 15360)          // cur [15360] (int)

// ushort offsets inside BF region
#define UB_Wb1 0
#define UB_Wb2 49152
#define UB_Wb3 65536
#define UB_Wv1 67584
#define UB_Wv2 100352
#define UB_Wv3 116736
#define UB_We1 133120
#define UB_We2 182272
#define UB_We3 198656

__device__ inline float gelu_f(float x){
  return 0.5f*x*(1.0f + erff(x*0.70710678118654752f));
}
__device__ inline unsigned fenc(float f){
  unsigned u = __float_as_uint(f);
  return (u & 0x80000000u) ? ~u : (u | 0x80000000u);
}
__device__ inline float fdec(unsigned u){
  return __uint_as_float((u & 0x80000000u) ? (u & 0x7fffffffu) : ~u);
}
__device__ inline ushort bfb(float f){
  __bf16 h = (__bf16)f;
  return __builtin_bit_cast(unsigned short, h);
}

// ================= MFMA edge-MLP machinery =================
// Orientation: D' = W (A, M=outcols) x X^T (B, N=edges).
// A-frag: lane reads W[wm*64+mt*16+(l&15)][kt*32+(l>>4)*8 .. +8] (bf16 row-major)
// B-frag: lane reads X[edge][same k range] (8 fp32 -> cvt)
// C/D  : lane holds edge=(l&15), outcols (l>>4)*4+0..3.

struct EMem {
  ushort act[128][128];   // inter-layer activations, XOR-swizzled (32 KB)
  int   idx[256];         // src[128], dst[128]
  float cp[256];          // column stat partials
};

// kC variant: fp32 V-buffer unioned over act (64 KB), + sorted-slot arrays
struct EMemC {
  union { ushort act[128][128]; float vbuf[128][128]; };
  int pe[128];            // original edge id per sorted slot
  int idx[256];           // src[128], dst[128] (of sorted edges)
};

union FB { s16x8 v; ushort u[8]; };

__device__ inline s16x8 load_x8(const float* __restrict__ p){
  float4 a = *(const float4*)p;
  float4 b = *(const float4*)(p+4);
  FB r;
  r.u[0]=bfb(a.x); r.u[1]=bfb(a.y); r.u[2]=bfb(a.z); r.u[3]=bfb(a.w);
  r.u[4]=bfb(b.x); r.u[5]=bfb(b.y); r.u[6]=bfb(b.z); r.u[7]=bfb(b.w);
  return r.v;
}

// XOR swizzle: permute 16B blocks within a row by row&7 (G4 fix)
__device__ inline void st_act4(ushort (*act)[128], int e, int obase,
                               float g0,float g1,float g2,float g3){
  short4 s;
  s.x=(short)bfb(g0); s.y=(short)bfb(g1); s.z=(short)bfb(g2); s.w=(short)bfb(g3);
  *(short4*)&act[e][obase ^ ((e&7)<<3)] = s;
}
__device__ inline s16x8 ld_act(ushort (*act)[128], int e, int k0){
  return *(const s16x8*)&act[e][k0 ^ ((e&7)<<3)];
}

__device__ inline void zacc(f32x4 (&a)[4][4]){
  #pragma unroll
  for(int i=0;i<4;++i)
    #pragma unroll
    for(int j=0;j<4;++j) a[i][j] = (f32x4){0.f,0.f,0.f,0.f};
}

// K=128 layer from LDS activations: acc += W x act^T
__device__ inline void mm_lds(const ushort* __restrict__ Wb, ushort (*act)[128],
                              int wm, int wn, int el, int kq, f32x4 (&acc)[4][4])
{
  #pragma unroll
  for (int kt=0; kt<4; ++kt){
    s16x8 af[4], bfr[4];
    #pragma unroll
    for (int mt=0;mt<4;++mt)
      af[mt] = *(const s16x8*)&Wb[(wm*64+mt*16+el)*128 + kt*32 + kq*8];
    #pragma unroll
    for (int nt=0;nt<4;++nt)
      bfr[nt] = ld_act(act, wn*64+nt*16+el, kt*32+kq*8);
    #pragma unroll
    for (int mt=0;mt<4;++mt)
      #pragma unroll
      for (int nt=0;nt<4;++nt)
        acc[mt][nt] = MFMA16(af[mt], bfr[nt], acc[mt][nt]);
  }
}

// bias + gelu + store to LDS act (next layer's input)
__device__ inline void intf(f32x4 (&acc)[4][4], const float* __restrict__ bias,
                            ushort (*act)[128], int wm, int wn, int el, int kq)
{
  #pragma unroll
  for (int mt=0;mt<4;++mt){
    int obase = wm*64+mt*16+kq*4;
    float4 bb = *(const float4*)&bias[obase];
    #pragma unroll
    for (int nt=0;nt<4;++nt){
      int e = wn*64+nt*16+el;
      st_act4(act, e, obase,
        gelu_f(acc[mt][nt][0]+bb.x), gelu_f(acc[mt][nt][1]+bb.y),
        gelu_f(acc[mt][nt][2]+bb.z), gelu_f(acc[mt][nt][3]+bb.w));
    }
  }
}

// layer1 with 3 segments [gather g0 | identity gi | gather g2], K=384
__device__ inline void edge_l1_3seg(const float* __restrict__ gV, const float* __restrict__ gI,
    const int* idx, const ushort* __restrict__ W1, int rowbase,
    int wm, int wn, int el, int kq, f32x4 (&acc)[4][4])
{
  #pragma unroll
  for (int seg=0; seg<3; ++seg){
    const float* rp[4];
    #pragma unroll
    for (int nt=0; nt<4; ++nt){
      int eloc = wn*64+nt*16+el;
      int g;
      if (seg==0) g = idx[eloc];
      else if (seg==1){ int e=rowbase+eloc; g = (e<EE)?e:(EE-1); }
      else g = idx[128+eloc];
      rp[nt] = ((seg==1)?gI:gV) + (size_t)g*128 + kq*8;
    }
    #pragma unroll
    for (int kt=0; kt<4; ++kt){
      s16x8 af[4], bfr[4];
      #pragma unroll
      for (int mt=0;mt<4;++mt)
        af[mt] = *(const s16x8*)&W1[(wm*64+mt*16+el)*384 + seg*128 + kt*32 + kq*8];
      #pragma unroll
      for (int nt=0;nt<4;++nt)
        bfr[nt] = load_x8(rp[nt] + kt*32);
      #pragma unroll
      for (int mt=0;mt<4;++mt)
        #pragma unroll
        for (int nt=0;nt<4;++nt)
          acc[mt][nt] = MFMA16(af[mt], bfr[nt], acc[mt][nt]);
    }
  }
}

// ---------------- counting sort of edges by src ----------------
__global__ void kHist(const int* __restrict__ eidx, int* __restrict__ cnt){
  int e = blockIdx.x*256 + threadIdx.x;
  if (e < EE) atomicAdd(&cnt[eidx[e]], 1);
}

__global__ void kScan(const int* __restrict__ cnt, int* __restrict__ cur){
  __shared__ int part[256];
  __shared__ int excl[256];
  int t = threadIdx.x;
  int base = t*60;           // 256*60 = 15360 >= NN
  int s = 0;
  for (int i=0;i<60;++i) s += cnt[base+i];
  part[t] = s;
  __syncthreads();
  if (t==0){ int r=0; for (int i=0;i<256;++i){ excl[i]=r; r+=part[i]; } }
  __syncthreads();
  int run = excl[t];
  for (int i=0;i<60;++i){ int c = cnt[base+i]; cur[base+i] = run; run += c; }
}

__global__ void kScat(const int* __restrict__ eidx, int* __restrict__ cur,
                      int* __restrict__ perm){
  int e = blockIdx.x*256 + threadIdx.x;
  if (e < EE){
    int p = atomicAdd(&cur[eidx[e]], 1);
    perm[p] = e;
  }
}

// ---------------- kA: Bias MLP + segment max ----------------
__global__ void kA_mfma(const float* __restrict__ hV, const float* __restrict__ hE,
    const int* __restrict__ eidx,
    const ushort* __restrict__ W1, const ushort* __restrict__ W2, const ushort* __restrict__ W3,
    const float* __restrict__ b1, const float* __restrict__ b2, const float* __restrict__ b3,
    float* __restrict__ wbuf, unsigned* __restrict__ mArr)
{
  __shared__ EMem sm;
  int t = threadIdx.x, lane = t&63, wave = t>>6;
  int el = lane&15, kq = lane>>4, wm = wave>>1, wn = wave&1;
  int rowbase = blockIdx.x*128;
  if (t<128){ int e=rowbase+t; if(e>=EE) e=EE-1; sm.idx[t]=eidx[e]; sm.idx[128+t]=eidx[EE+e]; }
  __syncthreads();
  f32x4 acc[4][4]; zacc(acc);
  edge_l1_3seg(hV, hE, sm.idx, W1, rowbase, wm, wn, el, kq, acc);
  intf(acc, b1, sm.act, wm, wn, el, kq);
  __syncthreads();
  zacc(acc);
  mm_lds(W2, sm.act, wm, wn, el, kq, acc);
  __syncthreads();
  intf(acc, b2, sm.act, wm, wn, el, kq);
  __syncthreads();
  // L3: 128 -> 4 heads (W3 zero-padded to 16 rows); each wave: edges wave*32..+31
  f32x4 a3[2]; a3[0]=(f32x4){0.f,0.f,0.f,0.f}; a3[1]=(f32x4){0.f,0.f,0.f,0.f};
  #pragma unroll
  for (int kt=0;kt<4;++kt){
    s16x8 af = *(const s16x8*)&W3[el*128 + kt*32 + kq*8];
    #pragma unroll
    for (int q=0;q<2;++q){
      s16x8 bv = ld_act(sm.act, wave*32+q*16+el, kt*32+kq*8);
      a3[q] = MFMA16(af, bv, a3[q]);
    }
  }
  if (kq==0){
    #pragma unroll
    for (int q=0;q<2;++q){
      int eloc = wave*32+q*16+el, e = rowbase+eloc;
      if (e<EE){
        const float SC = 0.17677669529663687f;  // 1/sqrt(32)
        float4 w;
        w.x=(a3[q][0]+b3[0])*SC; w.y=(a3[q][1]+b3[1])*SC;
        w.z=(a3[q][2]+b3[2])*SC; w.w=(a3[q][3]+b3[3])*SC;
        *(float4*)&wbuf[e*4] = w;
        unsigned s4 = (unsigned)sm.idx[eloc]*4;
        atomicMax(&mArr[s4+0],fenc(w.x));
        atomicMax(&mArr[s4+1],fenc(w.y));
        atomicMax(&mArr[s4+2],fenc(w.z));
        atomicMax(&mArr[s4+3],fenc(w.w));
      }
    }
  }
}

// ---------------- kB: exp + segment sum ----------------
__global__ void kB(const int* __restrict__ eidx, const unsigned* __restrict__ mArr,
                   float* __restrict__ wbuf, float* __restrict__ sArr)
{
  int tid = blockIdx.x*256 + threadIdx.x;
  if (tid >= EE*4) return;
  int e = tid >> 2, h = tid & 3;
  int srcn = eidx[e];
  float ex = expf(wbuf[tid] - fdec(mArr[srcn*4 + h]));
  wbuf[tid] = ex;
  atomicAdd(&sArr[srcn*4 + h], ex);
}

// ---------------- kC: V MLP on sorted edges + segmented reduce ----------------
__global__ void kC_mfma(const float* __restrict__ hV, const float* __restrict__ hE,
    const int* __restrict__ eidx, const int* __restrict__ perm,
    const ushort* __restrict__ W1, const ushort* __restrict__ W2, const ushort* __restrict__ W3,
    const float* __restrict__ b1, const float* __restrict__ b2, const float* __restrict__ b3,
    const float* __restrict__ wbuf, const float* __restrict__ sArr,
    float* __restrict__ agg)
{
  __shared__ EMemC sm;
  int t = threadIdx.x, lane = t&63, wave = t>>6;
  int el = lane&15, kq = lane>>4, wm = wave>>1, wn = wave&1;
  int rowbase = blockIdx.x*128;
  if (t<128){
    int slot = rowbase + t; if (slot >= EE) slot = EE-1;
    int pe = perm[slot];
    sm.pe[t] = pe;
    sm.idx[t] = eidx[pe];
    sm.idx[128+t] = eidx[EE+pe];
  }
  __syncthreads();
  f32x4 acc[4][4]; zacc(acc);
  // layer1 K=256: [hE gather(pe) | hV gather dst]
  #pragma unroll
  for (int seg=0; seg<2; ++seg){
    const float* rp[4];
    #pragma unroll
    for (int nt=0; nt<4; ++nt){
      int eloc = wn*64+nt*16+el;
      int g = (seg==0) ? sm.pe[eloc] : sm.idx[128+eloc];
      rp[nt] = ((seg==0)?hE:hV) + (size_t)g*128 + kq*8;
    }
    #pragma unroll
    for (int kt=0; kt<4; ++kt){
      s16x8 af[4], bfr[4];
      #pragma unroll
      for (int mt=0;mt<4;++mt)
        af[mt] = *(const s16x8*)&W1[(wm*64+mt*16+el)*256 + seg*128 + kt*32 + kq*8];
      #pragma unroll
      for (int nt=0;nt<4;++nt)
        bfr[nt] = load_x8(rp[nt] + kt*32);
      #pragma unroll
      for (int mt=0;mt<4;++mt)
        #pragma unroll
        for (int nt=0;nt<4;++nt)
          acc[mt][nt] = MFMA16(af[mt], bfr[nt], acc[mt][nt]);
    }
  }
  intf(acc, b1, sm.act, wm, wn, el, kq);
  __syncthreads();
  zacc(acc);
  mm_lds(W2, sm.act, wm, wn, el, kq, acc);
  __syncthreads();
  intf(acc, b2, sm.act, wm, wn, el, kq);
  __syncthreads();
  zacc(acc);
  mm_lds(W3, sm.act, wm, wn, el, kq, acc);
  __syncthreads();   // act (union vbuf) now dead for all waves
  // epilogue: attend*(V+b3) -> vbuf (fp32, XOR-swizzled 16B blocks)
  #pragma unroll
  for (int nt=0;nt<4;++nt){
    int e = wn*64+nt*16+el;
    int slot = rowbase + e;
    float at4[4];
    if (slot < EE){
      int pe = sm.pe[e];
      int sn = sm.idx[e];
      float4 wv = *(const float4*)&wbuf[pe*4];
      float4 sv = *(const float4*)&sArr[sn*4];
      at4[0]=wv.x/sv.x; at4[1]=wv.y/sv.y; at4[2]=wv.z/sv.z; at4[3]=wv.w/sv.w;
    } else {
      at4[0]=at4[1]=at4[2]=at4[3]=0.f;
    }
    #pragma unroll
    for (int mt=0;mt<4;++mt){
      int o = wm*64+mt*16+kq*4;
      float4 bb = *(const float4*)&b3[o];
      float a = at4[o>>5];
      float4 v;
      v.x = a*(acc[mt][nt][0]+bb.x);
      v.y = a*(acc[mt][nt][1]+bb.y);
      v.z = a*(acc[mt][nt][2]+bb.z);
      v.w = a*(acc[mt][nt][3]+bb.w);
      *(float4*)&sm.vbuf[e][o ^ ((e&7)<<2)] = v;
    }
  }
  __syncthreads();
  // segmented reduction over sorted edges: thread t -> col (t&127), edges half (t>>7)
  {
    int col = t & 127, h2 = t >> 7;
    int e0 = h2*64;
    float run = 0.f;
    int cursrc = sm.idx[e0];
    for (int e = e0; e < e0+64; ++e){
      int s = sm.idx[e];
      if (s != cursrc){
        atomicAdd(&agg[(size_t)cursrc*128 + col], run);
        run = 0.f; cursrc = s;
      }
      run += sm.vbuf[e][col ^ ((e&7)<<2)];
    }
    atomicAdd(&agg[(size_t)cursrc*128 + col], run);
  }
}

// ---------------- kI: Edge MLP + residual + statsE ----------------
__global__ void kI_mfma(const float* __restrict__ hVfin, const float* __restrict__ hE,
    const int* __restrict__ eidx,
    const ushort* __restrict__ W1, const ushort* __restrict__ W2, const ushort* __restrict__ W3,
    const float* __restrict__ b1, const float* __restrict__ b2, const float* __restrict__ b3,
    float* __restrict__ hEout, float* __restrict__ stat)
{
  __shared__ EMem sm;
  int t = threadIdx.x, lane = t&63, wave = t>>6;
  int el = lane&15, kq = lane>>4, wm = wave>>1, wn = wave&1;
  int rowbase = blockIdx.x*128;
  if (t<128){ int e=rowbase+t; if(e>=EE) e=EE-1; sm.idx[t]=eidx[e]; sm.idx[128+t]=eidx[EE+e]; }
  __syncthreads();
  f32x4 acc[4][4]; zacc(acc);
  edge_l1_3seg(hVfin, hE, sm.idx, W1, rowbase, wm, wn, el, kq, acc);
  intf(acc, b1, sm.act, wm, wn, el, kq);
  __syncthreads();
  zacc(acc);
  mm_lds(W2, sm.act, wm, wn, el, kq, acc);
  __syncthreads();
  intf(acc, b2, sm.act, wm, wn, el, kq);
  __syncthreads();
  zacc(acc);
  mm_lds(W3, sm.act, wm, wn, el, kq, acc);
  // epilogue: pre = hE + msg + b3 ; stats
  float ps[4][4], pq[4][4];
  #pragma unroll
  for (int mt=0;mt<4;++mt)
    #pragma unroll
    for (int r=0;r<4;++r){ ps[mt][r]=0.f; pq[mt][r]=0.f; }
  #pragma unroll
  for (int nt=0;nt<4;++nt){
    int eloc = wn*64+nt*16+el, e = rowbase+eloc;
    if (e < EE){
      #pragma unroll
      for (int mt=0;mt<4;++mt){
        int o = wm*64+mt*16+kq*4;
        float4 bb = *(const float4*)&b3[o];
        float4 h0 = *(const float4*)&hE[(size_t)e*128+o];
        float4 v;
        v.x = h0.x+acc[mt][nt][0]+bb.x;
        v.y = h0.y+acc[mt][nt][1]+bb.y;
        v.z = h0.z+acc[mt][nt][2]+bb.z;
        v.w = h0.w+acc[mt][nt][3]+bb.w;
        *(float4*)&hEout[(size_t)e*128+o] = v;
        ps[mt][0]+=v.x; ps[mt][1]+=v.y; ps[mt][2]+=v.z; ps[mt][3]+=v.w;
        pq[mt][0]+=v.x*v.x; pq[mt][1]+=v.y*v.y; pq[mt][2]+=v.z*v.z; pq[mt][3]+=v.w*v.w;
      }
    }
  }
  __syncthreads();
  sm.cp[t] = 0.f;
  __syncthreads();
  #pragma unroll
  for (int mt=0;mt<4;++mt){
    int o = wm*64+mt*16+kq*4;
    #pragma unroll
    for (int r=0;r<4;++r){
      atomicAdd(&sm.cp[o+r], ps[mt][r]);
      atomicAdd(&sm.cp[128+o+r], pq[mt][r]);
    }
  }
  __syncthreads();
  atomicAdd(&stat[t], sm.cp[t]);
}

// ================= fp32 node path (unchanged machinery) =================
struct SMem {
  float act[128][132];
  float ws[16][128];
  int   idx[256];
  float cp[256];
};

__device__ inline void zero8(float (&a)[8][8]){
  #pragma unroll
  for (int i=0;i<8;++i)
    #pragma unroll
    for (int j=0;j<8;++j) a[i][j]=0.f;
}

__device__ inline void stage_chunk(const float* __restrict__ src, int width, int kbase,
                                   const int* idxArr, int rowbase, int limit,
                                   float (*act)[132], int t)
{
  __syncthreads();
  int k = t & 127, half = t >> 7;
  const float* sp = src + kbase + k;
  #pragma unroll
  for (int i = 0; i < 64; i += 4){
    int r = half*64 + i;
    float v[4];
    #pragma unroll
    for (int j = 0; j < 4; ++j){
      int rr = r + j;
      int g = idxArr ? idxArr[rr] : ((rowbase + rr < limit) ? (rowbase + rr) : (limit-1));
      v[j] = sp[g*width];
    }
    *(float4*)&act[k][r] = make_float4(v[0],v[1],v[2],v[3]);
  }
  __syncthreads();
}

__device__ inline void stage_aff(const float* __restrict__ src, const float* __restrict__ ab,
                                 int rowbase, int limit, float (*act)[132], int t)
{
  __syncthreads();
  int k = t & 127, half = t >> 7;
  float a = ab[k], c = ab[128+k];
  const float* sp = src + k;
  #pragma unroll
  for (int i = 0; i < 64; i += 4){
    int r = half*64 + i;
    float v[4];
    #pragma unroll
    for (int j = 0; j < 4; ++j){
      int rr = r + j;
      int g = (rowbase + rr < limit) ? (rowbase + rr) : (limit-1);
      v[j] = fmaf(sp[g*128], a, c);
    }
    *(float4*)&act[k][r] = make_float4(v[0],v[1],v[2],v[3]);
  }
  __syncthreads();
}

__device__ inline void gemm128(const float* __restrict__ Wt, int ldw, int kbase, int ccol,
                               float (&acc)[8][8], float (*act)[132], float (*ws)[128], int t)
{
  int c0 = (t & 15)*8, r0 = (t >> 4)*8;
  for (int ks = 0; ks < 128; ks += 16){
    __syncthreads();
    {
      int kk = t >> 4, c = (t & 15)*8;
      const float* wp = Wt + (kbase + ks + kk)*ldw + ccol + c;
      float4 w0 = *(const float4*)wp;
      float4 w1 = *(const float4*)(wp + 4);
      *(float4*)&ws[kk][c]   = w0;
      *(float4*)&ws[kk][c+4] = w1;
    }
    __syncthreads();
    #pragma unroll
    for (int kk = 0; kk < 16; ++kk){
      int k = ks + kk;
      float4 xa = *(float4*)&act[k][r0];
      float4 xb = *(float4*)&act[k][r0+4];
      float4 wa = *(float4*)&ws[kk][c0];
      float4 wb = *(float4*)&ws[kk][c0+4];
      float x[8] = {xa.x,xa.y,xa.z,xa.w,xb.x,xb.y,xb.z,xb.w};
      float w[8] = {wa.x,wa.y,wa.z,wa.w,wb.x,wb.y,wb.z,wb.w};
      #pragma unroll
      for (int ri=0;ri<8;++ri)
        #pragma unroll
        for (int ci=0;ci<8;++ci)
          acc[ri][ci] = fmaf(x[ri], w[ci], acc[ri][ci]);
    }
  }
}

__device__ inline void block_stats(const float (&ps)[8], const float (&pq)[8],
                                   float* __restrict__ stat, float* cp, int t)
{
  int c0=(t&15)*8;
  __syncthreads();
  cp[t] = 0.f;
  __syncthreads();
  #pragma unroll
  for (int ci=0;ci<8;++ci){
    atomicAdd(&cp[c0+ci], ps[ci]);
    atomicAdd(&cp[128+c0+ci], pq[ci]);
  }
  __syncthreads();
  if (t < 128){
    atomicAdd(&stat[t], cp[t]);
    atomicAdd(&stat[128+t], cp[128+t]);
  }
}

// ---------------- weight prep ----------------
struct TP { const float* s[3]; float* d[3]; };

__global__ void kT(TP a){
  const int Os[3]={128,512,128};
  const int Is[3]={128,128,512};
  int b = blockIdx.x, mi = 0, off = 0;
  for (;;){
    int nb = (Os[mi]*Is[mi] + 4095) >> 12;
    if (b < off + nb) break;
    off += nb; ++mi;
  }
  int O = Os[mi], I = Is[mi], sz = O*I;
  int e0 = (b - off) * 4096;
  int eEnd = (e0 + 4096 < sz) ? (e0 + 4096) : sz;
  for (int e = e0 + (int)threadIdx.x; e < eEnd; e += 256){
    int o = e / I, i = e - o*I;
    a.d[mi][i*O + o] = a.s[mi][e];
  }
}

struct CP9 { const float* s[9]; };

__global__ void kConv(CP9 a, ushort* __restrict__ dst){
  const int SZ[9]   = {49152,16384,2048,32768,16384,16384,49152,16384,16384};
  const int SRCSZ[9]= {49152,16384, 512,32768,16384,16384,49152,16384,16384};
  int b = blockIdx.x, mi=0, off=0;
  for(;;){ int nb=(SZ[mi]+1023)>>10; if (b<off+nb) break; off+=nb; ++mi; }
  int base=0;
  for(int j=0;j<mi;++j) base+=SZ[j];
  int e0=(b-off)*1024;
  int eE=(e0+1024<SZ[mi])?(e0+1024):SZ[mi];
  for (int i=e0+(int)threadIdx.x; i<eE; i+=256){
    float v = (i < SRCSZ[mi]) ? a.s[mi][i] : 0.f;
    dst[base+i] = bfb(v);
  }
}

// ---------------- kD: Wo GEMM + residual + stats0 ----------------
__global__ __launch_bounds__(256,2) void kD(
    const float* __restrict__ hV, const float* __restrict__ aggM, const float* __restrict__ Wot,
    float* __restrict__ xbuf, float* __restrict__ stat)
{
  __shared__ SMem sm;
  int t = threadIdx.x;
  int rowbase = blockIdx.x * 128;
  float acc[8][8];
  zero8(acc);
  stage_chunk(aggM, 128, 0, nullptr, rowbase, NN, sm.act, t);
  gemm128(Wot, 128, 0, 0, acc, sm.act, sm.ws, t);
  int c0=(t&15)*8, r0=(t>>4)*8;
  float ps[8]={0,0,0,0,0,0,0,0}, pq[8]={0,0,0,0,0,0,0,0};
  #pragma unroll
  for (int ri=0;ri<8;++ri){
    int g = rowbase + r0 + ri;
    if (g < NN){
      float4 h0 = *(const float4*)&hV[g*128+c0];
      float4 h1 = *(const float4*)&hV[g*128+c0+4];
      float hv[8]={h0.x,h0.y,h0.z,h0.w,h1.x,h1.y,h1.z,h1.w};
      float v[8];
      #pragma unroll
      for (int ci=0;ci<8;++ci){
        v[ci]=hv[ci]+acc[ri][ci];
        ps[ci]+=v[ci]; pq[ci]+=v[ci]*v[ci];
      }
      *(float4*)&xbuf[g*128+c0]   = make_float4(v[0],v[1],v[2],v[3]);
      *(float4*)&xbuf[g*128+c0+4] = make_float4(v[4],v[5],v[6],v[7]);
    }
  }
  block_stats(ps,pq,stat,sm.cp,t);
}

// ---------------- kFin ----------------
__global__ void kFin(const float* __restrict__ stat, const float* __restrict__ gw,
                     const float* __restrict__ bw, float* __restrict__ ab, float invcnt)
{
  int t = threadIdx.x;  // 128
  float mean = stat[t]*invcnt;
  float var  = fmaxf(stat[128+t]*invcnt - mean*mean, 0.f);
  float inv  = rsqrtf(var + 1e-5f);
  float a = inv * gw[t];
  ab[t] = a;
  ab[128+t] = fmaf(-mean, a, bw[t]);
}

// ---------------- kF1 ----------------
__global__ __launch_bounds__(256,2) void kF1(
    const float* __restrict__ xbuf, const float* __restrict__ ab0,
    const float* __restrict__ Wd1t, const float* __restrict__ bd1,
    float* __restrict__ hidden)
{
  __shared__ SMem sm;
  int t = threadIdx.x;
  int rowbase = blockIdx.x * 128;
  stage_aff(xbuf, ab0, rowbase, NN, sm.act, t);
  int c0=(t&15)*8, r0=(t>>4)*8;
  for (int cc=0; cc<4; ++cc){
    float acc[8][8];
    zero8(acc);
    gemm128(Wd1t, 512, 0, cc*128, acc, sm.act, sm.ws, t);
    float bd[8];
    #pragma unroll
    for (int ci=0;ci<8;++ci) bd[ci]=bd1[cc*128+c0+ci];
    #pragma unroll
    for (int ri=0;ri<8;++ri){
      int g = rowbase + r0 + ri;
      if (g < NN){
        float v[8];
        #pragma unroll
        for (int ci=0;ci<8;++ci) v[ci]=gelu_f(acc[ri][ci]+bd[ci]);
        *(float4*)&hidden[g*512+cc*128+c0]   = make_float4(v[0],v[1],v[2],v[3]);
        *(float4*)&hidden[g*512+cc*128+c0+4] = make_float4(v[4],v[5],v[6],v[7]);
      }
    }
  }
}

// ---------------- kF2 ----------------
__global__ __launch_bounds__(256,2) void kF2(
    const float* __restrict__ xbuf, const float* __restrict__ hidden,
    const float* __restrict__ ab0, const float* __restrict__ Wd2t, const float* __restrict__ bd2,
    float* __restrict__ hVout, float* __restrict__ stat)
{
  __shared__ SMem sm;
  int t = threadIdx.x;
  int rowbase = blockIdx.x * 128;
  float acc[8][8];
  zero8(acc);
  for (int cc=0; cc<4; ++cc){
    stage_chunk(hidden, 512, cc*128, nullptr, rowbase, NN, sm.act, t);
    gemm128(Wd2t, 128, cc*128, 0, acc, sm.act, sm.ws, t);
  }
  int c0=(t&15)*8, r0=(t>>4)*8;
  float a0v[8],c0v[8],bd[8];
  #pragma unroll
  for (int ci=0;ci<8;++ci){ a0v[ci]=ab0[c0+ci]; c0v[ci]=ab0[128+c0+ci]; bd[ci]=bd2[c0+ci]; }
  float ps[8]={0,0,0,0,0,0,0,0}, pq[8]={0,0,0,0,0,0,0,0};
  #pragma unroll
  for (int ri=0;ri<8;++ri){
    int g = rowbase + r0 + ri;
    if (g < NN){
      float4 x0 = *(const float4*)&xbuf[g*128+c0];
      float4 x1 = *(const float4*)&xbuf[g*128+c0+4];
      float xv[8]={x0.x,x0.y,x0.z,x0.w,x1.x,x1.y,x1.z,x1.w};
      float v[8];
      #pragma unroll
      for (int ci=0;ci<8;++ci){
        v[ci] = fmaf(xv[ci], a0v[ci], c0v[ci]) + acc[ri][ci] + bd[ci];
        ps[ci]+=v[ci]; pq[ci]+=v[ci]*v[ci];
      }
      *(float4*)&hVout[g*128+c0]   = make_float4(v[0],v[1],v[2],v[3]);
      *(float4*)&hVout[g*128+c0+4] = make_float4(v[4],v[5],v[6],v[7]);
    }
  }
  block_stats(ps,pq,stat,sm.cp,t);
}

// ---------------- kNorm ----------------
__global__ void kNorm(float* __restrict__ x, const float* __restrict__ ab, int total)
{
  int i = (blockIdx.x*256 + (int)threadIdx.x)*4;
  if (i >= total) return;
  float4 v = *(float4*)&x[i];
  int c = i & 127;
  v.x = fmaf(v.x, ab[c],   ab[128+c]);
  v.y = fmaf(v.y, ab[c+1], ab[128+c+1]);
  v.z = fmaf(v.z, ab[c+2], ab[128+c+2]);
  v.w = fmaf(v.w, ab[c+3], ab[128+c+3]);
  *(float4*)&x[i] = v;
}

// ---------------- host ----------------
extern "C" void kernel_launch(void* const* d_in, const int* in_sizes, int n_in,
                              void* d_out, int out_size, void* d_ws, size_t ws_size,
                              hipStream_t stream)
{
  const float* hV  =(const float*)d_in[0];
  const float* hE  =(const float*)d_in[1];
  const int*   eidx=(const int*)  d_in[2];
  const float* Wv1 =(const float*)d_in[4];
  const float* bv1 =(const float*)d_in[5];
  const float* Wv2 =(const float*)d_in[6];
  const float* bv2 =(const float*)d_in[7];
  const float* Wv3 =(const float*)d_in[8];
  const float* bv3 =(const float*)d_in[9];
  const float* Wb1 =(const float*)d_in[10];
  const float* bb1 =(const float*)d_in[11];
  const float* Wb2 =(const float*)d_in[12];
  const float* bb2 =(const float*)d_in[13];
  const float* Wb3 =(const float*)d_in[14];
  const float* bb3 =(const float*)d_in[15];
  const float* Wo  =(const float*)d_in[16];
  const float* g0  =(const float*)d_in[17];
  const float* b0  =(const float*)d_in[18];
  const float* g1  =(const float*)d_in[19];
  const float* b1  =(const float*)d_in[20];
  const float* Wd1 =(const float*)d_in[21];
  const float* bd1 =(const float*)d_in[22];
  const float* Wd2 =(const float*)d_in[23];
  const float* bd2 =(const float*)d_in[24];
  const float* We1 =(const float*)d_in[25];
  const float* be1 =(const float*)d_in[26];
  const float* We2 =(const float*)d_in[27];
  const float* be2 =(const float*)d_in[28];
  const float* We3 =(const float*)d_in[29];
  const float* be3 =(const float*)d_in[30];
  const float* ge  =(const float*)d_in[31];
  const float* bEn =(const float*)d_in[32];

  float* W  = (float*)d_ws;
  float* dO = (float*)d_out;
  ushort* WB = (ushort*)(W + O_BF);

  // 1. node weights fp32 transpose
  TP tp;
  tp.s[0]=Wo;  tp.d[0]=W+O_Wot;
  tp.s[1]=Wd1; tp.d[1]=W+O_Wd1t;
  tp.s[2]=Wd2; tp.d[2]=W+O_Wd2t;
  kT<<<36,256,0,stream>>>(tp);

  // 2. edge weights -> bf16 (row-major [O][K])
  CP9 c9;
  c9.s[0]=Wb1; c9.s[1]=Wb2; c9.s[2]=Wb3;
  c9.s[3]=Wv1; c9.s[4]=Wv2; c9.s[5]=Wv3;
  c9.s[6]=We1; c9.s[7]=We2; c9.s[8]=We3;
  kConv<<<210,256,0,stream>>>(c9, WB);

  // 3. counting sort of edges by src
  hipMemsetAsync(W + O_CNT, 0, 15360*sizeof(int), stream);
  kHist<<<(EE+255)/256,256,0,stream>>>(eidx, (int*)(W+O_CNT));
  kScan<<<1,256,0,stream>>>((const int*)(W+O_CNT), (int*)(W+O_CUR));
  kScat<<<(EE+255)/256,256,0,stream>>>(eidx, (int*)(W+O_CUR), (int*)(W+O_PERM));

  // 4. zero m / s / agg / stats
  hipMemsetAsync(W + O_M, 0, (size_t)(O_AB - O_M)*sizeof(float), stream);

  // 5. attention
  kA_mfma<<<(EE+127)/128,256,0,stream>>>(hV,hE,eidx, WB+UB_Wb1,WB+UB_Wb2,WB+UB_Wb3,
                                         bb1,bb2,bb3, W+O_WB,(unsigned*)(W+O_M));
  kB<<<(EE*4+255)/256,256,0,stream>>>(eidx,(const unsigned*)(W+O_M), W+O_WB, W+O_S);
  kC_mfma<<<(EE+127)/128,256,0,stream>>>(hV,hE,eidx,(const int*)(W+O_PERM),
                                         WB+UB_Wv1,WB+UB_Wv2,WB+UB_Wv3,
                                         bv1,bv2,bv3, W+O_WB, W+O_S, W+O_AGG);

  // 6. node update (fp32)
  kD<<<(NN+127)/128,256,0,stream>>>(hV, W+O_AGG, W+O_Wot, W+O_XB, W+O_STAT);
  kFin<<<1,128,0,stream>>>(W+O_STAT, g0, b0, W+O_AB, 1.0f/NN);
  kF1<<<(NN+127)/128,256,0,stream>>>(W+O_XB, W+O_AB, W+O_Wd1t, bd1, W+O_HID);
  kF2<<<(NN+127)/128,256,0,stream>>>(W+O_XB, W+O_HID, W+O_AB, W+O_Wd2t, bd2,
                                     dO, W+O_STAT+256);
  kFin<<<1,128,0,stream>>>(W+O_STAT+256, g1, b1, W+O_AB+256, 1.0f/NN);
  kNorm<<<(NN*128/4+255)/256,256,0,stream>>>(dO, W+O_AB+256, NN*128);

  // 7. edge update (bf16 MFMA)
  kI_mfma<<<(EE+127)/128,256,0,stream>>>(dO, hE, eidx, WB+UB_We1,WB+UB_We2,WB+UB_We3,
                                         be1,be2,be3, dO+(size_t)NN*128, W+O_STAT+512);
  kFin<<<1,128,0,stream>>>(W+O_STAT+512, ge, bEn, W+O_AB+512, 1.0f/EE);
  kNorm<<<(EE*128/4+255)/256,256,0,stream>>>(dO+(size_t)NN*128, W+O_AB+512, EE*128);
}